// Round 1
// 835.234 us; speedup vs baseline: 1.0392x; 1.0392x over previous
//
#include <hip/hip_runtime.h>
#include <stdint.h>

typedef __attribute__((ext_vector_type(8))) short short8;
typedef __attribute__((ext_vector_type(4))) float f32x4;

typedef const __attribute__((address_space(1))) unsigned int* gas_u32p;
typedef __attribute__((address_space(3))) unsigned int* las_u32p;

__device__ __forceinline__ unsigned short f2bf(float f){
  union{float f; unsigned u;} v; v.f = f;
  unsigned r = v.u + 0x7FFFu + ((v.u >> 16) & 1u);
  return (unsigned short)(r >> 16);
}
__device__ __forceinline__ void dec8(uint4 d, float* r){
  union{unsigned a; float f;} t;
  t.a = (d.x & 0xFFFFu) << 16; r[0]=t.f; t.a = d.x & 0xFFFF0000u; r[1]=t.f;
  t.a = (d.y & 0xFFFFu) << 16; r[2]=t.f; t.a = d.y & 0xFFFF0000u; r[3]=t.f;
  t.a = (d.z & 0xFFFFu) << 16; r[4]=t.f; t.a = d.z & 0xFFFF0000u; r[5]=t.f;
  t.a = (d.w & 0xFFFFu) << 16; r[6]=t.f; t.a = d.w & 0xFFFF0000u; r[7]=t.f;
}

// Pack conv_w [128][64][3][3] -> wA [ks=18][m=128][kk=32] bf16, k = (dh*3+dw)*64 + cin
__global__ __launch_bounds__(256) void k_prep(const float* __restrict__ cw,
                                              unsigned short* __restrict__ wA){
  int i = blockIdx.x*256 + threadIdx.x;
  if(i >= 18*128*32) return;
  int kk = i & 31, m = (i >> 5) & 127, ks = i >> 12;
  int k = ks*32 + kk;
  int pos = k >> 6, cin = k & 63;
  int dh = pos/3, dw = pos - dh*3;
  wA[i] = f2bf(cw[((m*64 + cin)*3 + dh)*3 + dw]);
}

// Transpose+convert x [b][c][h][w] fp32 -> xbf [b][h][w][c] bf16.
// One block per (b,h): 64c x 64w tile through LDS.
__global__ __launch_bounds__(256) void k_xbf(const float* __restrict__ x,
                                             unsigned short* __restrict__ xbf){
  const int h = blockIdx.x, b = blockIdx.y;
  __shared__ float L[64][65];
  const int t = threadIdx.x;
  #pragma unroll
  for(int i=0;i<4;++i){
    int idx = i*256 + t;            // 1024 float4 units
    int c = idx >> 4, w0 = (idx & 15) * 4;
    const float* p = x + (((size_t)b*64 + c)*512 + h)*64 + w0;
    float4 v = *(const float4*)p;
    L[c][w0] = v.x; L[c][w0+1] = v.y; L[c][w0+2] = v.z; L[c][w0+3] = v.w;
  }
  __syncthreads();
  unsigned short* dst = xbf + (((size_t)b*512 + h) << 12);
  #pragma unroll
  for(int i=0;i<8;++i){
    int idx = i*256 + t;            // 2048 u32 units
    int w = idx >> 5, c2 = (idx & 31)*2;
    unsigned pk = (unsigned)f2bf(L[c2][w]) | ((unsigned)f2bf(L[c2+1][w]) << 16);
    *(unsigned*)(dst + (w<<6) + c2) = pk;
  }
}

// Implicit-GEMM conv: block = (b, 2 output rows). M=128 cout x N=128 (2h x 64w), K=576.
// x staged via global_load_lds from pre-converted xbf[b][h][w][c]; LDS linear
// [4 rows][64 w][64 c] bf16 with XOR swizzle folded into the GLOBAL source address
// (swz(w) = ((w>>1)&7)<<4 on the 128B cin-row) and re-applied on ds_read.
// n mapping: n = wave*32 + 2*(lane&15) + nt -> adjacent w pairs per lane (packed stores).
__global__ __launch_bounds__(256) void k_conv(
    const unsigned short* __restrict__ xbf, const unsigned short* __restrict__ wA,
    unsigned short* __restrict__ craw, float* __restrict__ sum_slots,
    float* __restrict__ sq_slots)
{
  const int b = blockIdx.y;
  const int bx = blockIdx.x;
  const int hx = (bx & 7)*32 + (bx >> 3);   // XCD-aware h-tile swizzle (bijective, 256=8*32)
  const int h0 = hx * 2;
  __shared__ __align__(16) unsigned short xs[4*64*64];   // 32 KB, linear
  __shared__ float red[2][128];
  const int t = threadIdx.x;
  const int lane = t & 63, wv = t >> 6;
  // stage 4 halo rows: wave wv stages row wv (8 KB) via 8x global_load_lds dwordx4
  {
    int hin = h0 - 1 + wv;
    hin = hin < 0 ? 1 : (hin > 511 ? 510 : hin);   // reflect pad
    const unsigned short* rsrc = xbf + (((size_t)b*512 + hin) << 12);
    unsigned short* ldsrow = &xs[wv*4096];
    #pragma unroll
    for(int it=0; it<8; ++it){
      int o = it*1024 + lane*16;                   // byte offset within 8 KB row
      int w = o >> 7;
      int q = o & 127;
      int so = (w << 7) + (q ^ (((w >> 1) & 7) << 4));   // pre-swizzled source
      __builtin_amdgcn_global_load_lds(
          (gas_u32p)(const void*)((const char*)rsrc + so),
          (las_u32p)(void*)(ldsrow + it*512), 16, 0, 0);
    }
  }
  const int r15 = lane & 15, quad = lane >> 4;
  const int hr = wv >> 1;                 // output row within block
  const int w_off = (wv & 1) * 32;        // w tile base
  f32x4 acc[8][2];
  #pragma unroll
  for(int mt=0;mt<8;++mt){
    #pragma unroll
    for(int nt=0;nt<2;++nt){ f32x4 z = {0.f,0.f,0.f,0.f}; acc[mt][nt] = z; }
  }
  short8 a_cur[8], a_nxt[8];
  const unsigned short* wbase = wA + r15*32 + quad*8;
  #pragma unroll
  for(int mt=0;mt<8;++mt) a_cur[mt] = *(const short8*)(wbase + mt*512);
  __syncthreads();
  const char* xsb = (const char*)xs;
  for(int ks=0; ks<18; ++ks){
    if(ks < 17){
      const unsigned short* wk = wbase + (ks+1)*4096;
      #pragma unroll
      for(int mt=0;mt<8;++mt) a_nxt[mt] = *(const short8*)(wk + mt*512);
    }
    const int pos = ks >> 1;
    const int dh = pos/3, dw = pos - dh*3;
    const int coff = (ks & 1)*64 + quad*16;        // byte offset in 128B cin-row
    const int rr = hr + dh;
    short8 bfr[2];
    #pragma unroll
    for(int nt=0;nt<2;++nt){
      int wi = w_off + 2*r15 + nt + dw - 1;
      wi = wi < 0 ? 1 : (wi > 63 ? 62 : wi);       // reflect pad
      int addr = rr*8192 + (wi << 7) + (coff ^ (((wi >> 1) & 7) << 4));
      bfr[nt] = *(const short8*)(xsb + addr);
    }
    #pragma unroll
    for(int mt=0;mt<8;++mt){
      acc[mt][0] = __builtin_amdgcn_mfma_f32_16x16x32_bf16(a_cur[mt], bfr[0], acc[mt][0], 0,0,0);
      acc[mt][1] = __builtin_amdgcn_mfma_f32_16x16x32_bf16(a_cur[mt], bfr[1], acc[mt][1], 0,0,0);
    }
    #pragma unroll
    for(int mt=0;mt<8;++mt) a_cur[mt] = a_nxt[mt];
  }
  // epilogue: D col=lane&15 -> w pair (w_off+2*r15+{0,1}), row=quad*4+rg (m).
  // Pack the adjacent-w pair into one dword store (64B/quad segments).
  {
    size_t obase = (((size_t)b*128)*512 + (size_t)(h0+hr))*64 + w_off + 2*r15;
    #pragma unroll
    for(int mt=0;mt<8;++mt){
      #pragma unroll
      for(int rg=0;rg<4;++rg){
        int co = mt*16 + quad*4 + rg;
        unsigned pk = (unsigned)f2bf(acc[mt][0][rg]) | ((unsigned)f2bf(acc[mt][1][rg]) << 16);
        *(unsigned*)(craw + obase + (size_t)co*32768) = pk;
      }
    }
  }
  // BN1 stats: per-cout sum/sumsq, reduce within quad-lanes -> LDS -> slotted global atomics
  if(t < 128){ red[0][t] = 0.f; red[1][t] = 0.f; }
  __syncthreads();
  #pragma unroll
  for(int mt=0;mt<8;++mt){
    #pragma unroll
    for(int rg=0;rg<4;++rg){
      float v0 = acc[mt][0][rg], v1 = acc[mt][1][rg];
      float s = v0 + v1;
      float q = v0*v0 + v1*v1;
      #pragma unroll
      for(int m=1;m<16;m<<=1){ s += __shfl_xor(s, m); q += __shfl_xor(q, m); }
      if(r15 == 0){
        int co = mt*16 + quad*4 + rg;
        atomicAdd(&red[0][co], s);
        atomicAdd(&red[1][co], q);
      }
    }
  }
  __syncthreads();
  if(t < 128){
    int slot = bx & 63;
    atomicAdd(&sum_slots[t*64 + slot], red[0][t]);
    atomicAdd(&sq_slots[t*64 + slot], red[1][t]);
  }
}

__global__ __launch_bounds__(256) void k_bn1fin(
    const float* __restrict__ sum_slots, const float* __restrict__ sq_slots,
    const float* __restrict__ g1, const float* __restrict__ b1,
    float* __restrict__ s1, float* __restrict__ t1)
{
  int c = threadIdx.x; if(c >= 128) return;
  double S = 0.0, Q = 0.0;
  for(int s=0;s<64;++s){ S += (double)sum_slots[c*64+s]; Q += (double)sq_slots[c*64+s]; }
  const double N = 524288.0;
  double mu = S/N, var = Q/N - mu*mu;
  float sc = (float)((double)g1[c] / sqrt(var + 1e-5));
  s1[c] = sc;
  t1[c] = (float)((double)b1[c] - mu*(double)sc);
}

// read conv_raw, h=relu(bn1), emit xm=mean_w(h), S_h/Q_h per channel, LN partials per batch
__global__ __launch_bounds__(256) void k_passB(
    const unsigned short* __restrict__ craw, const float* __restrict__ s1,
    const float* __restrict__ t1, float* __restrict__ xm,
    float* __restrict__ Sh, float* __restrict__ Qh,
    float* __restrict__ lnS, float* __restrict__ lnQ)
{
  const int c = blockIdx.x, b = blockIdx.y;
  const int t = threadIdx.x, wv = t >> 6, l = t & 63;
  const float sc = s1[c], sf = t1[c];
  const unsigned short* base = craw + (((size_t)b*128 + c)*512)*64;
  float* xrow = xm + ((size_t)b*128 + c)*512;
  float sa = 0.f, qa = 0.f, la = 0.f;
  for(int it=0; it<16; ++it){
    int row = it*32 + wv*8 + (l >> 3);
    int w0 = (l & 7)*8;
    uint4 d = *(const uint4*)(base + (size_t)row*64 + w0);
    float r[8]; dec8(d, r);
    float tot = 0.f;
    #pragma unroll
    for(int j=0;j<8;++j){
      float v = sc*r[j] + sf;
      v = v > 0.f ? v : 0.f;
      tot += v; sa += v; qa += v*v;
    }
    tot += __shfl_xor(tot, 1); tot += __shfl_xor(tot, 2); tot += __shfl_xor(tot, 4);
    if((l & 7) == 0){
      float mv = tot * (1.f/64.f);
      xrow[row] = mv;
      la += mv*mv;
    }
  }
  #pragma unroll
  for(int m=1;m<64;m<<=1){
    sa += __shfl_xor(sa, m); qa += __shfl_xor(qa, m); la += __shfl_xor(la, m);
  }
  __shared__ float rs[4], rq[4], rl[4];
  if(l == 0){ rs[wv]=sa; rq[wv]=qa; rl[wv]=la; }
  __syncthreads();
  if(t == 0){
    float S = rs[0]+rs[1]+rs[2]+rs[3];
    float Q = rq[0]+rq[1]+rq[2]+rq[3];
    float L = rl[0]+rl[1]+rl[2]+rl[3];
    atomicAdd(&Sh[c], S);
    atomicAdd(&Qh[c], Q);
    atomicAdd(&lnS[b], S * (1.f/64.f));
    atomicAdd(&lnQ[b], L);
  }
}

__global__ __launch_bounds__(256) void k_lnfin(
    const float* __restrict__ lnS, const float* __restrict__ lnQ,
    float* __restrict__ ln_mu, float* __restrict__ ln_rs)
{
  int b = threadIdx.x; if(b >= 16) return;
  double mu = (double)lnS[b] / 65536.0;
  double var = (double)lnQ[b] / 65536.0 - mu*mu;
  ln_mu[b] = (float)mu;
  ln_rs[b] = (float)(1.0 / sqrt(var + 1e-5));
}

__global__ __launch_bounds__(256) void k_xn(
    const float* __restrict__ xm, const float* __restrict__ ln_mu,
    const float* __restrict__ ln_rs, float* __restrict__ xn)
{
  int i = blockIdx.x*256 + threadIdx.x;
  if(i >= 16*128*512) return;
  int b = i >> 16;
  xn[i] = (xm[i] - ln_mu[b]) * ln_rs[b];
}

// scores f[b,h,k] = sum_c xn[b,c,h]*xn[b,c,k] / sqrt(128); 64x64 tile per block
__global__ __launch_bounds__(256) void k_f(const float* __restrict__ xn, float* __restrict__ f)
{
  const int kt = blockIdx.x, ht = blockIdx.y, b = blockIdx.z;
  __shared__ __align__(16) float Xh[128][64];
  __shared__ __align__(16) float Xk[128][64];
  const int t = threadIdx.x;
  const int h0 = ht*64, k0 = kt*64;
  for(int i=0;i<32;++i){
    int idx = t + i*256;
    int c = idx >> 6, hh = idx & 63;
    const float* src = xn + ((size_t)b*128 + c)*512;
    Xh[c][hh] = src[h0 + hh];
    Xk[c][hh] = src[k0 + hh];
  }
  __syncthreads();
  const int tx = t & 15, ty = t >> 4;
  float acc[4][4] = {{0}};
  for(int c=0;c<128;++c){
    f32x4 a = *(const f32x4*)&Xh[c][ty*4];
    f32x4 bb = *(const f32x4*)&Xk[c][tx*4];
    #pragma unroll
    for(int i=0;i<4;++i)
      #pragma unroll
      for(int j=0;j<4;++j) acc[i][j] += a[i]*bb[j];
  }
  const float s = 0.088388347648318447f;
  #pragma unroll
  for(int i=0;i<4;++i){
    f32x4 o;
    o[0]=acc[i][0]*s; o[1]=acc[i][1]*s; o[2]=acc[i][2]*s; o[3]=acc[i][3]*s;
    *(f32x4*)&f[((size_t)b*512 + h0 + ty*4 + i)*512 + k0 + tx*4] = o;
  }
}

// softmax over last axis, one row (512) per wave
__global__ __launch_bounds__(256) void k_sm(float* __restrict__ f)
{
  const int bid = blockIdx.x;
  const int b = bid >> 7, h4 = bid & 127;
  const int t = threadIdx.x, wv = t >> 6, l = t & 63;
  float* row = f + ((size_t)b*512 + h4*4 + wv)*512;
  f32x4 v0 = *(const f32x4*)&row[l*8];
  f32x4 v1 = *(const f32x4*)&row[l*8 + 4];
  float mx = v0[0];
  #pragma unroll
  for(int j=1;j<4;++j) mx = fmaxf(mx, v0[j]);
  #pragma unroll
  for(int j=0;j<4;++j) mx = fmaxf(mx, v1[j]);
  #pragma unroll
  for(int m=1;m<64;m<<=1) mx = fmaxf(mx, __shfl_xor(mx, m));
  float sum = 0.f;
  #pragma unroll
  for(int j=0;j<4;++j){ v0[j] = __expf(v0[j]-mx); sum += v0[j]; }
  #pragma unroll
  for(int j=0;j<4;++j){ v1[j] = __expf(v1[j]-mx); sum += v1[j]; }
  #pragma unroll
  for(int m=1;m<64;m<<=1) sum += __shfl_xor(sum, m);
  float inv = 1.f / sum;
  #pragma unroll
  for(int j=0;j<4;++j){ v0[j] *= inv; v1[j] *= inv; }
  *(f32x4*)&row[l*8] = v0;
  *(f32x4*)&row[l*8+4] = v1;
}

// y1[b,m,k] = sum_c g_w[m,c]*xn[b,c,k] + g_b[m]; block = (64-k tile, b), all 128 m
__global__ __launch_bounds__(256) void k_y1(
    const float* __restrict__ xn, const float* __restrict__ gw,
    const float* __restrict__ gb, float* __restrict__ y1)
{
  const int kt = blockIdx.x, b = blockIdx.y;
  __shared__ __align__(16) float GT[128][128];
  __shared__ __align__(16) float XN[128][68];
  const int t = threadIdx.x;
  const int k0 = kt*64;
  for(int i=0;i<64;++i){
    int idx = t + i*256;
    int o = idx & 127, c = idx >> 7;
    GT[c][o] = gw[o*128 + c];
  }
  for(int i=0;i<32;++i){
    int idx = t + i*256;
    int c = idx >> 6, kk = idx & 63;
    XN[c][kk] = xn[((size_t)b*128 + c)*512 + k0 + kk];
  }
  __syncthreads();
  const int tx = t & 15, ty = t >> 4;
  float acc[8][4] = {{0}};
  for(int c=0;c<128;++c){
    f32x4 a0 = *(const f32x4*)&GT[c][ty*8];
    f32x4 a1 = *(const f32x4*)&GT[c][ty*8+4];
    f32x4 bv = *(const f32x4*)&XN[c][tx*4];
    #pragma unroll
    for(int j=0;j<4;++j){
      #pragma unroll
      for(int i=0;i<4;++i){ acc[i][j] += a0[i]*bv[j]; acc[i+4][j] += a1[i]*bv[j]; }
    }
  }
  #pragma unroll
  for(int i=0;i<8;++i){
    int m = ty*8 + i;
    float bias = gb[m];
    f32x4 o;
    #pragma unroll
    for(int j=0;j<4;++j) o[j] = acc[i][j] + bias;
    *(f32x4*)&y1[((size_t)b*128 + m)*512 + k0 + tx*4] = o;
  }
}

// y2t[b,h,m] = sum_k f[b,h,k]*y1[b,m,k]; block = (32-h tile, b), K=512 chunked by 64
__global__ __launch_bounds__(256) void k_y2(
    const float* __restrict__ f, const float* __restrict__ y1,
    float* __restrict__ y2t)
{
  const int ht = blockIdx.x, b = blockIdx.y;
  __shared__ __align__(16) float FT[64][36];
  __shared__ __align__(16) float Y1T[64][132];
  const int t = threadIdx.x;
  const int h0 = ht*32;
  const int tx = t & 15, ty = t >> 4;
  float acc[2][8] = {{0}};
  for(int kc=0;kc<8;++kc){
    int k0 = kc*64;
    __syncthreads();
    for(int i=0;i<8;++i){
      int idx = t + i*256;
      int k = idx & 63, hh = idx >> 6;
      FT[k][hh] = f[((size_t)b*512 + h0 + hh)*512 + k0 + k];
    }
    for(int i=0;i<32;++i){
      int idx = t + i*256;
      int k = idx & 63, m = idx >> 6;
      Y1T[k][m] = y1[((size_t)b*128 + m)*512 + k0 + k];
    }
    __syncthreads();
    for(int kk=0;kk<64;++kk){
      float a0 = FT[kk][ty*2], a1 = FT[kk][ty*2+1];
      f32x4 b0 = *(const f32x4*)&Y1T[kk][tx*8];
      f32x4 b1 = *(const f32x4*)&Y1T[kk][tx*8+4];
      #pragma unroll
      for(int j=0;j<4;++j){
        acc[0][j]   += a0*b0[j]; acc[1][j]   += a1*b0[j];
        acc[0][j+4] += a0*b1[j]; acc[1][j+4] += a1*b1[j];
      }
    }
  }
  #pragma unroll
  for(int i=0;i<2;++i){
    int h = h0 + ty*2 + i;
    f32x4 o0, o1;
    #pragma unroll
    for(int j=0;j<4;++j){ o0[j]=acc[i][j]; o1[j]=acc[i][j+4]; }
    float* dst = y2t + ((size_t)b*512 + h)*128 + tx*8;
    *(f32x4*)dst = o0;
    *(f32x4*)(dst+4) = o1;
  }
}

// y3[b,o,h] = sum_m out_w[o,m]*y2t[b,h,m] + out_b[o]; block = (32-h tile, b)
__global__ __launch_bounds__(256) void k_y3(
    const float* __restrict__ y2t, const float* __restrict__ ow,
    const float* __restrict__ obv, float* __restrict__ y3)
{
  const int ht = blockIdx.x, b = blockIdx.y;
  __shared__ __align__(16) float WT[128][128];
  __shared__ __align__(16) float Y2[128][36];
  const int t = threadIdx.x;
  const int h0 = ht*32;
  for(int i=0;i<64;++i){
    int idx = t + i*256;
    int o = idx & 127, m = idx >> 7;
    WT[m][o] = ow[o*128 + m];
  }
  for(int i=0;i<16;++i){
    int idx = t + i*256;
    int m = idx & 127, hh = idx >> 7;
    Y2[m][hh] = y2t[((size_t)b*512 + h0 + hh)*128 + m];
  }
  __syncthreads();
  const int tx = t & 15, ty = t >> 4;
  float acc[8][2] = {{0}};
  for(int m=0;m<128;++m){
    f32x4 a0 = *(const f32x4*)&WT[m][ty*8];
    f32x4 a1 = *(const f32x4*)&WT[m][ty*8+4];
    float b0 = Y2[m][tx*2], b1 = Y2[m][tx*2+1];
    #pragma unroll
    for(int i=0;i<4;++i){
      acc[i][0]   += a0[i]*b0; acc[i][1]   += a0[i]*b1;
      acc[i+4][0] += a1[i]*b0; acc[i+4][1] += a1[i]*b1;
    }
  }
  #pragma unroll
  for(int i=0;i<8;++i){
    int o = ty*8 + i;
    float bias = obv[o];
    float2 v; v.x = acc[i][0] + bias; v.y = acc[i][1] + bias;
    *(float2*)&y3[((size_t)b*128 + o)*512 + h0 + tx*2] = v;
  }
}

// per-channel sums of y3, y3^2, y3*xm (one block per channel, deterministic)
__global__ __launch_bounds__(256) void k_ystats(
    const float* __restrict__ y3, const float* __restrict__ xm,
    float* __restrict__ Sy, float* __restrict__ Syy, float* __restrict__ Sxy)
{
  const int c = blockIdx.x;
  const int t = threadIdx.x, wv = t >> 6, l = t & 63;
  float s=0.f, ss=0.f, sx=0.f;
  for(int i=0;i<32;++i){
    int idx = t + i*256;
    int b = idx >> 9, h = idx & 511;
    size_t off = ((size_t)b*128 + c)*512 + h;
    float v = y3[off], u = xm[off];
    s += v; ss += v*v; sx += v*u;
  }
  #pragma unroll
  for(int m=1;m<64;m<<=1){ s += __shfl_xor(s,m); ss += __shfl_xor(ss,m); sx += __shfl_xor(sx,m); }
  __shared__ float r1[4], r2[4], r3[4];
  if(l == 0){ r1[wv]=s; r2[wv]=ss; r3[wv]=sx; }
  __syncthreads();
  if(t == 0){
    Sy[c]  = r1[0]+r1[1]+r1[2]+r1[3];
    Syy[c] = r2[0]+r2[1]+r2[2]+r2[3];
    Sxy[c] = r3[0]+r3[1]+r3[2]+r3[3];
  }
}

// BN2 stats via decomposition: S2 = Sh + W*Sy ; Q2 = Qh + 2W*Sxy + W*Syy
__global__ __launch_bounds__(256) void k_bn2fin(
    const float* __restrict__ Sh, const float* __restrict__ Qh,
    const float* __restrict__ Sy, const float* __restrict__ Syy,
    const float* __restrict__ Sxy, const float* __restrict__ g2,
    const float* __restrict__ b2, float* __restrict__ s2, float* __restrict__ t2)
{
  int c = threadIdx.x; if(c >= 128) return;
  const double N = 524288.0;
  double S2 = (double)Sh[c] + 64.0*(double)Sy[c];
  double Q2 = (double)Qh[c] + 128.0*(double)Sxy[c] + 64.0*(double)Syy[c];
  double mu = S2/N, var = Q2/N - mu*mu;
  float sc = (float)((double)g2[c] / sqrt(var + 1e-5));
  s2[c] = sc;
  t2[c] = (float)((double)b2[c] - mu*(double)sc);
}

// out = silu(bn2(relu(bn1(conv)) + y3))
__global__ __launch_bounds__(256) void k_final(
    const unsigned short* __restrict__ craw, const float* __restrict__ s1,
    const float* __restrict__ t1, const float* __restrict__ y3,
    const float* __restrict__ s2, const float* __restrict__ t2,
    float* __restrict__ out)
{
  const int c = blockIdx.x, b = blockIdx.y;
  const int t = threadIdx.x, wv = t >> 6, l = t & 63;
  const float a1 = s1[c], c1 = t1[c], a2 = s2[c], c2 = t2[c];
  const size_t rb = ((size_t)b*128 + c)*512;
  const unsigned short* base = craw + rb*64;
  const float* yrow = y3 + rb;
  float* ob = out + rb*64;
  for(int it=0; it<16; ++it){
    int row = it*32 + wv*8 + (l >> 3);
    int w0 = (l & 7)*8;
    uint4 d = *(const uint4*)(base + (size_t)row*64 + w0);
    float yv = yrow[row];
    float r[8]; dec8(d, r);
    f32x4 o0, o1;
    #pragma unroll
    for(int j=0;j<8;++j){
      float h = a1*r[j] + c1; h = h > 0.f ? h : 0.f;
      float z = a2*(h + yv) + c2;
      float val = z / (1.f + __expf(-z));
      if(j < 4) o0[j] = val; else o1[j-4] = val;
    }
    *(f32x4*)(ob + (size_t)row*64 + w0) = o0;
    *(f32x4*)(ob + (size_t)row*64 + w0 + 4) = o1;
  }
}

extern "C" void kernel_launch(void* const* d_in, const int* in_sizes, int n_in,
                              void* d_out, int out_size, void* d_ws, size_t ws_size,
                              hipStream_t stream)
{
  const float* x      = (const float*)d_in[0];
  const float* conv_w = (const float*)d_in[1];
  const float* bn1_g  = (const float*)d_in[2];
  const float* bn1_b  = (const float*)d_in[3];
  const float* g_w    = (const float*)d_in[4];
  const float* g_b    = (const float*)d_in[5];
  const float* out_w  = (const float*)d_in[6];
  const float* out_b  = (const float*)d_in[7];
  const float* bn2_g  = (const float*)d_in[8];
  const float* bn2_b  = (const float*)d_in[9];
  float* out = (float*)d_out;
  char* ws = (char*)d_ws;

  // ws layout (needs ~138.7 MB)
  float* sum_slots = (float*)(ws);            // 128*64
  float* sq_slots  = (float*)(ws + 32768);    // 128*64
  float* Sh        = (float*)(ws + 65536);    // 128
  float* Qh        = (float*)(ws + 66048);    // 128
  float* lnS       = (float*)(ws + 66560);    // 16
  float* lnQ       = (float*)(ws + 66624);    // 16  -- zero region ends at 66688
  float* s1        = (float*)(ws + 66688);
  float* t1        = (float*)(ws + 67200);
  float* ln_mu     = (float*)(ws + 67712);
  float* ln_rs     = (float*)(ws + 67776);
  float* Sy        = (float*)(ws + 67840);
  float* Syy       = (float*)(ws + 68352);
  float* Sxy       = (float*)(ws + 68864);
  float* s2        = (float*)(ws + 69376);
  float* t2        = (float*)(ws + 69888);
  unsigned short* wA = (unsigned short*)(ws + 70400);      // 147456 B
  float* y3        = (float*)(ws + 217856);                // 4 MB
  unsigned short* craw = (unsigned short*)(ws + 4412160);  // 134217728 B

  // intermediates that die before k_final live in d_out (268 MB) as scratch
  float* xm  = out;                 // 1M floats
  float* xn  = out + (1u<<20);
  float* y1  = out + 2*(1u<<20);
  float* y2t = out + 3*(1u<<20);
  float* f   = out + 4*(1u<<20);    // ends ~34.5 MB
  unsigned short* xbf = (unsigned short*)((char*)out + (size_t)64*1024*1024); // 67 MB, dies before k_final

  hipMemsetAsync(ws, 0, 66688, stream);
  hipLaunchKernelGGL(k_prep,   dim3(288),      dim3(256), 0, stream, conv_w, wA);
  hipLaunchKernelGGL(k_xbf,    dim3(512,16),   dim3(256), 0, stream, x, xbf);
  hipLaunchKernelGGL(k_conv,   dim3(256,16),   dim3(256), 0, stream, xbf, wA, craw, sum_slots, sq_slots);
  hipLaunchKernelGGL(k_bn1fin, dim3(1),        dim3(128), 0, stream, sum_slots, sq_slots, bn1_g, bn1_b, s1, t1);
  hipLaunchKernelGGL(k_passB,  dim3(128,16),   dim3(256), 0, stream, craw, s1, t1, xm, Sh, Qh, lnS, lnQ);
  hipLaunchKernelGGL(k_lnfin,  dim3(1),        dim3(64),  0, stream, lnS, lnQ, ln_mu, ln_rs);
  hipLaunchKernelGGL(k_xn,     dim3(4096),     dim3(256), 0, stream, xm, ln_mu, ln_rs, xn);
  hipLaunchKernelGGL(k_f,      dim3(8,8,16),   dim3(256), 0, stream, xn, f);
  hipLaunchKernelGGL(k_sm,     dim3(2048),     dim3(256), 0, stream, f);
  hipLaunchKernelGGL(k_y1,     dim3(8,16),     dim3(256), 0, stream, xn, g_w, g_b, y1);
  hipLaunchKernelGGL(k_y2,     dim3(16,16),    dim3(256), 0, stream, f, y1, y2t);
  hipLaunchKernelGGL(k_y3,     dim3(16,16),    dim3(256), 0, stream, y2t, out_w, out_b, y3);
  hipLaunchKernelGGL(k_ystats, dim3(128),      dim3(256), 0, stream, y3, xm, Sy, Syy, Sxy);
  hipLaunchKernelGGL(k_bn2fin, dim3(1),        dim3(128), 0, stream, Sh, Qh, Sy, Syy, Sxy, bn2_g, bn2_b, s2, t2);
  hipLaunchKernelGGL(k_final,  dim3(128,16),   dim3(256), 0, stream, craw, s1, t1, y3, s2, t2, out);
}

// Round 2
// 798.489 us; speedup vs baseline: 1.0870x; 1.0460x over previous
//
#include <hip/hip_runtime.h>
#include <stdint.h>

typedef __attribute__((ext_vector_type(8))) short short8;
typedef __attribute__((ext_vector_type(4))) float f32x4;

typedef const __attribute__((address_space(1))) unsigned int* gas_u32p;
typedef __attribute__((address_space(3))) unsigned int* las_u32p;

__device__ __forceinline__ unsigned short f2bf(float f){
  union{float f; unsigned u;} v; v.f = f;
  unsigned r = v.u + 0x7FFFu + ((v.u >> 16) & 1u);
  return (unsigned short)(r >> 16);
}
__device__ __forceinline__ void dec8(uint4 d, float* r){
  union{unsigned a; float f;} t;
  t.a = (d.x & 0xFFFFu) << 16; r[0]=t.f; t.a = d.x & 0xFFFF0000u; r[1]=t.f;
  t.a = (d.y & 0xFFFFu) << 16; r[2]=t.f; t.a = d.y & 0xFFFF0000u; r[3]=t.f;
  t.a = (d.z & 0xFFFFu) << 16; r[4]=t.f; t.a = d.z & 0xFFFF0000u; r[5]=t.f;
  t.a = (d.w & 0xFFFFu) << 16; r[6]=t.f; t.a = d.w & 0xFFFF0000u; r[7]=t.f;
}

// Pack conv_w [128][64][3][3] -> wA [ks=18][m=128][kk=32] bf16, k = (dh*3+dw)*64 + cin
__global__ __launch_bounds__(256) void k_prep(const float* __restrict__ cw,
                                              unsigned short* __restrict__ wA){
  int i = blockIdx.x*256 + threadIdx.x;
  if(i >= 18*128*32) return;
  int kk = i & 31, m = (i >> 5) & 127, ks = i >> 12;
  int k = ks*32 + kk;
  int pos = k >> 6, cin = k & 63;
  int dh = pos/3, dw = pos - dh*3;
  wA[i] = f2bf(cw[((m*64 + cin)*3 + dh)*3 + dw]);
}

// Transpose+convert x [b][c][h][w] fp32 -> xbf [b][h][w][c] bf16.
__global__ __launch_bounds__(256) void k_xbf(const float* __restrict__ x,
                                             unsigned short* __restrict__ xbf){
  const int h = blockIdx.x, b = blockIdx.y;
  __shared__ float L[64][65];
  const int t = threadIdx.x;
  #pragma unroll
  for(int i=0;i<4;++i){
    int idx = i*256 + t;            // 1024 float4 units
    int c = idx >> 4, w0 = (idx & 15) * 4;
    const float* p = x + (((size_t)b*64 + c)*512 + h)*64 + w0;
    float4 v = *(const float4*)p;
    L[c][w0] = v.x; L[c][w0+1] = v.y; L[c][w0+2] = v.z; L[c][w0+3] = v.w;
  }
  __syncthreads();
  unsigned short* dst = xbf + (((size_t)b*512 + h) << 12);
  #pragma unroll
  for(int i=0;i<8;++i){
    int idx = i*256 + t;            // 2048 u32 units
    int w = idx >> 5, c2 = (idx & 31)*2;
    unsigned pk = (unsigned)f2bf(L[c2][w]) | ((unsigned)f2bf(L[c2+1][w]) << 16);
    *(unsigned*)(dst + (w<<6) + c2) = pk;
  }
}

// Implicit-GEMM conv v3: block = (b, 4 output rows). Each wave owns one 64-w row:
// acc[8][4] (M=128 x N=64 per wave, K=576, 576 MFMA/wave). LDS: 6 halo rows,
// linear, XOR swizzle folded into global source + precomputed P[nt][dw] read bases.
__global__ __launch_bounds__(256, 2) void k_conv(
    const unsigned short* __restrict__ xbf, const unsigned short* __restrict__ wA,
    unsigned short* __restrict__ craw, float* __restrict__ sum_slots,
    float* __restrict__ sq_slots)
{
  const int b = blockIdx.y;
  const int bx = blockIdx.x;                 // 0..127
  const int hx = (bx & 7)*16 + (bx >> 3);    // XCD swizzle, bijective (128 = 8*16)
  const int h0 = hx * 4;
  __shared__ __align__(16) unsigned short xs[6*4096];   // 48 KB linear
  __shared__ float red[2][128];
  const int t = threadIdx.x;
  const int lane = t & 63, wv = t >> 6;
  // stage 6 halo rows (rows h0-1 .. h0+4), 8 KB each via global_load_lds dwordx4
  for(int r = wv; r < 6; r += 4){
    int hin = h0 - 1 + r;
    hin = hin < 0 ? 1 : (hin > 511 ? 510 : hin);   // reflect pad
    const unsigned short* rsrc = xbf + (((size_t)b*512 + hin) << 12);
    unsigned short* ldsrow = &xs[r*4096];
    #pragma unroll
    for(int it=0; it<8; ++it){
      int o = it*1024 + lane*16;                   // byte offset within 8 KB row
      int w = o >> 7;
      int q = o & 127;
      int so = (w << 7) + (q ^ (((w >> 1) & 7) << 4));   // pre-swizzled source
      __builtin_amdgcn_global_load_lds(
          (gas_u32p)(const void*)((const char*)rsrc + so),
          (las_u32p)(void*)(ldsrow + it*512), 16, 0, 0);
    }
  }
  const int r15 = lane & 15, quad = lane >> 4;
  // Precompute swizzled LDS byte-offsets: nt covers w = (nt>>1)*32 + 2*r15 + (nt&1)
  int P[4][3];
  #pragma unroll
  for(int nt=0;nt<4;++nt){
    int wn = (nt>>1)*32 + 2*r15 + (nt&1);
    #pragma unroll
    for(int dw=0;dw<3;++dw){
      int wi = wn + dw - 1;
      wi = wi < 0 ? 1 : (wi > 63 ? 62 : wi);     // reflect pad
      int s = ((wi >> 1) & 7) << 4;
      P[nt][dw] = (wi << 7) + ((quad*16) ^ (s & 0x30)) + (s & 0x40);
    }
  }
  f32x4 acc[8][4];
  #pragma unroll
  for(int mt=0;mt<8;++mt)
    #pragma unroll
    for(int nt=0;nt<4;++nt){ f32x4 z = {0.f,0.f,0.f,0.f}; acc[mt][nt] = z; }
  const unsigned short* wbase = wA + r15*32 + quad*8;
  __syncthreads();
  const char* xsb = (const char*)xs;
  #pragma unroll
  for(int ks=0; ks<18; ++ks){
    const int pos = ks >> 1;
    const int dh = pos/3, dw = pos - dh*3;
    const int kbit = (ks & 1) << 6;
    const int rowoff = (wv + dh)*8192;
    short8 a[8];
    const unsigned short* wk = wbase + ks*4096;
    #pragma unroll
    for(int mt=0;mt<8;++mt) a[mt] = *(const short8*)(wk + mt*512);
    short8 bfr[4];
    #pragma unroll
    for(int nt=0;nt<4;++nt)
      bfr[nt] = *(const short8*)(xsb + rowoff + (P[nt][dw] ^ kbit));
    #pragma unroll
    for(int mt=0;mt<8;++mt){
      #pragma unroll
      for(int nt=0;nt<4;++nt)
        acc[mt][nt] = __builtin_amdgcn_mfma_f32_16x16x32_bf16(a[mt], bfr[nt], acc[mt][nt], 0,0,0);
    }
  }
  // epilogue: D col=lane&15 -> w pairs (2*r15,2*r15+1) and (+32), row=quad*4+rg (m)
  {
    size_t obase = (((size_t)b*128)*512 + (size_t)(h0+wv))*64 + 2*r15;
    #pragma unroll
    for(int mt=0;mt<8;++mt){
      #pragma unroll
      for(int rg=0;rg<4;++rg){
        int co = mt*16 + quad*4 + rg;
        unsigned pk0 = (unsigned)f2bf(acc[mt][0][rg]) | ((unsigned)f2bf(acc[mt][1][rg]) << 16);
        unsigned pk1 = (unsigned)f2bf(acc[mt][2][rg]) | ((unsigned)f2bf(acc[mt][3][rg]) << 16);
        *(unsigned*)(craw + obase + (size_t)co*32768) = pk0;
        *(unsigned*)(craw + obase + (size_t)co*32768 + 32) = pk1;
      }
    }
  }
  // BN1 stats: per-cout sum/sumsq
  if(t < 128){ red[0][t] = 0.f; red[1][t] = 0.f; }
  __syncthreads();
  #pragma unroll
  for(int mt=0;mt<8;++mt){
    #pragma unroll
    for(int rg=0;rg<4;++rg){
      float s = acc[mt][0][rg] + acc[mt][1][rg] + acc[mt][2][rg] + acc[mt][3][rg];
      float q = acc[mt][0][rg]*acc[mt][0][rg] + acc[mt][1][rg]*acc[mt][1][rg]
              + acc[mt][2][rg]*acc[mt][2][rg] + acc[mt][3][rg]*acc[mt][3][rg];
      #pragma unroll
      for(int m=1;m<16;m<<=1){ s += __shfl_xor(s, m); q += __shfl_xor(q, m); }
      if(r15 == 0){
        int co = mt*16 + quad*4 + rg;
        atomicAdd(&red[0][co], s);
        atomicAdd(&red[1][co], q);
      }
    }
  }
  __syncthreads();
  if(t < 128){
    int slot = bx & 63;
    atomicAdd(&sum_slots[t*64 + slot], red[0][t]);
    atomicAdd(&sq_slots[t*64 + slot], red[1][t]);
  }
}

__global__ __launch_bounds__(256) void k_bn1fin(
    const float* __restrict__ sum_slots, const float* __restrict__ sq_slots,
    const float* __restrict__ g1, const float* __restrict__ b1,
    float* __restrict__ s1, float* __restrict__ t1)
{
  int c = threadIdx.x; if(c >= 128) return;
  double S = 0.0, Q = 0.0;
  for(int s=0;s<64;++s){ S += (double)sum_slots[c*64+s]; Q += (double)sq_slots[c*64+s]; }
  const double N = 524288.0;
  double mu = S/N, var = Q/N - mu*mu;
  float sc = (float)((double)g1[c] / sqrt(var + 1e-5));
  s1[c] = sc;
  t1[c] = (float)((double)b1[c] - mu*(double)sc);
}

// read conv_raw, h=relu(bn1), emit xm=mean_w(h), S_h/Q_h per channel, LN partials per batch
__global__ __launch_bounds__(256) void k_passB(
    const unsigned short* __restrict__ craw, const float* __restrict__ s1,
    const float* __restrict__ t1, float* __restrict__ xm,
    float* __restrict__ Sh, float* __restrict__ Qh,
    float* __restrict__ lnS, float* __restrict__ lnQ)
{
  const int c = blockIdx.x, b = blockIdx.y;
  const int t = threadIdx.x, wv = t >> 6, l = t & 63;
  const float sc = s1[c], sf = t1[c];
  const unsigned short* base = craw + (((size_t)b*128 + c)*512)*64;
  float* xrow = xm + ((size_t)b*128 + c)*512;
  float sa = 0.f, qa = 0.f, la = 0.f;
  for(int it=0; it<16; ++it){
    int row = it*32 + wv*8 + (l >> 3);
    int w0 = (l & 7)*8;
    uint4 d = *(const uint4*)(base + (size_t)row*64 + w0);
    float r[8]; dec8(d, r);
    float tot = 0.f;
    #pragma unroll
    for(int j=0;j<8;++j){
      float v = sc*r[j] + sf;
      v = v > 0.f ? v : 0.f;
      tot += v; sa += v; qa += v*v;
    }
    tot += __shfl_xor(tot, 1); tot += __shfl_xor(tot, 2); tot += __shfl_xor(tot, 4);
    if((l & 7) == 0){
      float mv = tot * (1.f/64.f);
      xrow[row] = mv;
      la += mv*mv;
    }
  }
  #pragma unroll
  for(int m=1;m<64;m<<=1){
    sa += __shfl_xor(sa, m); qa += __shfl_xor(qa, m); la += __shfl_xor(la, m);
  }
  __shared__ float rs[4], rq[4], rl[4];
  if(l == 0){ rs[wv]=sa; rq[wv]=qa; rl[wv]=la; }
  __syncthreads();
  if(t == 0){
    float S = rs[0]+rs[1]+rs[2]+rs[3];
    float Q = rq[0]+rq[1]+rq[2]+rq[3];
    float L = rl[0]+rl[1]+rl[2]+rl[3];
    atomicAdd(&Sh[c], S);
    atomicAdd(&Qh[c], Q);
    atomicAdd(&lnS[b], S * (1.f/64.f));
    atomicAdd(&lnQ[b], L);
  }
}

__global__ __launch_bounds__(256) void k_lnfin(
    const float* __restrict__ lnS, const float* __restrict__ lnQ,
    float* __restrict__ ln_mu, float* __restrict__ ln_rs)
{
  int b = threadIdx.x; if(b >= 16) return;
  double mu = (double)lnS[b] / 65536.0;
  double var = (double)lnQ[b] / 65536.0 - mu*mu;
  ln_mu[b] = (float)mu;
  ln_rs[b] = (float)(1.0 / sqrt(var + 1e-5));
}

// scores f[b,h,k] = sum_c xn_c_h*xn_c_k / sqrt(128); xn computed on the fly from xm
__global__ __launch_bounds__(256) void k_f(const float* __restrict__ xm,
    const float* __restrict__ ln_mu, const float* __restrict__ ln_rs,
    float* __restrict__ f)
{
  const int kt = blockIdx.x, ht = blockIdx.y, b = blockIdx.z;
  __shared__ __align__(16) float Xh[128][64];
  __shared__ __align__(16) float Xk[128][64];
  const int t = threadIdx.x;
  const int h0 = ht*64, k0 = kt*64;
  const float mu = ln_mu[b], rs = ln_rs[b];
  for(int i=0;i<32;++i){
    int idx = t + i*256;
    int c = idx >> 6, hh = idx & 63;
    const float* src = xm + ((size_t)b*128 + c)*512;
    Xh[c][hh] = (src[h0 + hh] - mu) * rs;
    Xk[c][hh] = (src[k0 + hh] - mu) * rs;
  }
  __syncthreads();
  const int tx = t & 15, ty = t >> 4;
  float acc[4][4] = {{0}};
  for(int c=0;c<128;++c){
    f32x4 a = *(const f32x4*)&Xh[c][ty*4];
    f32x4 bb = *(const f32x4*)&Xk[c][tx*4];
    #pragma unroll
    for(int i=0;i<4;++i)
      #pragma unroll
      for(int j=0;j<4;++j) acc[i][j] += a[i]*bb[j];
  }
  const float s = 0.088388347648318447f;
  #pragma unroll
  for(int i=0;i<4;++i){
    f32x4 o;
    o[0]=acc[i][0]*s; o[1]=acc[i][1]*s; o[2]=acc[i][2]*s; o[3]=acc[i][3]*s;
    *(f32x4*)&f[((size_t)b*512 + h0 + ty*4 + i)*512 + k0 + tx*4] = o;
  }
}

// softmax over last axis, one row (512) per wave
__global__ __launch_bounds__(256) void k_sm(float* __restrict__ f)
{
  const int bid = blockIdx.x;
  const int b = bid >> 7, h4 = bid & 127;
  const int t = threadIdx.x, wv = t >> 6, l = t & 63;
  float* row = f + ((size_t)b*512 + h4*4 + wv)*512;
  f32x4 v0 = *(const f32x4*)&row[l*8];
  f32x4 v1 = *(const f32x4*)&row[l*8 + 4];
  float mx = v0[0];
  #pragma unroll
  for(int j=1;j<4;++j) mx = fmaxf(mx, v0[j]);
  #pragma unroll
  for(int j=0;j<4;++j) mx = fmaxf(mx, v1[j]);
  #pragma unroll
  for(int m=1;m<64;m<<=1) mx = fmaxf(mx, __shfl_xor(mx, m));
  float sum = 0.f;
  #pragma unroll
  for(int j=0;j<4;++j){ v0[j] = __expf(v0[j]-mx); sum += v0[j]; }
  #pragma unroll
  for(int j=0;j<4;++j){ v1[j] = __expf(v1[j]-mx); sum += v1[j]; }
  #pragma unroll
  for(int m=1;m<64;m<<=1) sum += __shfl_xor(sum, m);
  float inv = 1.f / sum;
  #pragma unroll
  for(int j=0;j<4;++j){ v0[j] *= inv; v1[j] *= inv; }
  *(f32x4*)&row[l*8] = v0;
  *(f32x4*)&row[l*8+4] = v1;
}

// y1[b,m,k] = sum_c g_w[m,c]*xn[b,c,k] + g_b[m]; xn on the fly from xm
__global__ __launch_bounds__(256) void k_y1(
    const float* __restrict__ xm, const float* __restrict__ ln_mu,
    const float* __restrict__ ln_rs, const float* __restrict__ gw,
    const float* __restrict__ gb, float* __restrict__ y1)
{
  const int kt = blockIdx.x, b = blockIdx.y;
  __shared__ __align__(16) float GT[128][128];
  __shared__ __align__(16) float XN[128][68];
  const int t = threadIdx.x;
  const int k0 = kt*64;
  const float mu = ln_mu[b], rs = ln_rs[b];
  for(int i=0;i<64;++i){
    int idx = t + i*256;
    int o = idx & 127, c = idx >> 7;
    GT[c][o] = gw[o*128 + c];
  }
  for(int i=0;i<32;++i){
    int idx = t + i*256;
    int c = idx >> 6, kk = idx & 63;
    XN[c][kk] = (xm[((size_t)b*128 + c)*512 + k0 + kk] - mu) * rs;
  }
  __syncthreads();
  const int tx = t & 15, ty = t >> 4;
  float acc[8][4] = {{0}};
  for(int c=0;c<128;++c){
    f32x4 a0 = *(const f32x4*)&GT[c][ty*8];
    f32x4 a1 = *(const f32x4*)&GT[c][ty*8+4];
    f32x4 bv = *(const f32x4*)&XN[c][tx*4];
    #pragma unroll
    for(int j=0;j<4;++j){
      #pragma unroll
      for(int i=0;i<4;++i){ acc[i][j] += a0[i]*bv[j]; acc[i+4][j] += a1[i]*bv[j]; }
    }
  }
  #pragma unroll
  for(int i=0;i<8;++i){
    int m = ty*8 + i;
    float bias = gb[m];
    f32x4 o;
    #pragma unroll
    for(int j=0;j<4;++j) o[j] = acc[i][j] + bias;
    *(f32x4*)&y1[((size_t)b*128 + m)*512 + k0 + tx*4] = o;
  }
}

// y2t[b,h,m] = sum_k f[b,h,k]*y1[b,m,k]; block = (32-h tile, b), K=512 chunked by 64
__global__ __launch_bounds__(256) void k_y2(
    const float* __restrict__ f, const float* __restrict__ y1,
    float* __restrict__ y2t)
{
  const int ht = blockIdx.x, b = blockIdx.y;
  __shared__ __align__(16) float FT[64][36];
  __shared__ __align__(16) float Y1T[64][132];
  const int t = threadIdx.x;
  const int h0 = ht*32;
  const int tx = t & 15, ty = t >> 4;
  float acc[2][8] = {{0}};
  for(int kc=0;kc<8;++kc){
    int k0 = kc*64;
    __syncthreads();
    for(int i=0;i<8;++i){
      int idx = t + i*256;
      int k = idx & 63, hh = idx >> 6;
      FT[k][hh] = f[((size_t)b*512 + h0 + hh)*512 + k0 + k];
    }
    for(int i=0;i<32;++i){
      int idx = t + i*256;
      int k = idx & 63, m = idx >> 6;
      Y1T[k][m] = y1[((size_t)b*128 + m)*512 + k0 + k];
    }
    __syncthreads();
    for(int kk=0;kk<64;++kk){
      float a0 = FT[kk][ty*2], a1 = FT[kk][ty*2+1];
      f32x4 b0 = *(const f32x4*)&Y1T[kk][tx*8];
      f32x4 b1 = *(const f32x4*)&Y1T[kk][tx*8+4];
      #pragma unroll
      for(int j=0;j<4;++j){
        acc[0][j]   += a0*b0[j]; acc[1][j]   += a1*b0[j];
        acc[0][j+4] += a0*b1[j]; acc[1][j+4] += a1*b1[j];
      }
    }
  }
  #pragma unroll
  for(int i=0;i<2;++i){
    int h = h0 + ty*2 + i;
    f32x4 o0, o1;
    #pragma unroll
    for(int j=0;j<4;++j){ o0[j]=acc[i][j]; o1[j]=acc[i][j+4]; }
    float* dst = y2t + ((size_t)b*512 + h)*128 + tx*8;
    *(f32x4*)dst = o0;
    *(f32x4*)(dst+4) = o1;
  }
}

// y3[b,o,h] = sum_m out_w[o,m]*y2t[b,h,m] + out_b[o]; block = (32-h tile, b)
__global__ __launch_bounds__(256) void k_y3(
    const float* __restrict__ y2t, const float* __restrict__ ow,
    const float* __restrict__ obv, float* __restrict__ y3)
{
  const int ht = blockIdx.x, b = blockIdx.y;
  __shared__ __align__(16) float WT[128][128];
  __shared__ __align__(16) float Y2[128][36];
  const int t = threadIdx.x;
  const int h0 = ht*32;
  for(int i=0;i<64;++i){
    int idx = t + i*256;
    int o = idx & 127, m = idx >> 7;
    WT[m][o] = ow[o*128 + m];
  }
  for(int i=0;i<16;++i){
    int idx = t + i*256;
    int m = idx & 127, hh = idx >> 7;
    Y2[m][hh] = y2t[((size_t)b*512 + h0 + hh)*128 + m];
  }
  __syncthreads();
  const int tx = t & 15, ty = t >> 4;
  float acc[8][2] = {{0}};
  for(int m=0;m<128;++m){
    f32x4 a0 = *(const f32x4*)&WT[m][ty*8];
    f32x4 a1 = *(const f32x4*)&WT[m][ty*8+4];
    float b0 = Y2[m][tx*2], b1 = Y2[m][tx*2+1];
    #pragma unroll
    for(int i=0;i<4;++i){
      acc[i][0]   += a0[i]*b0; acc[i][1]   += a0[i]*b1;
      acc[i+4][0] += a1[i]*b0; acc[i+4][1] += a1[i]*b1;
    }
  }
  #pragma unroll
  for(int i=0;i<8;++i){
    int o = ty*8 + i;
    float bias = obv[o];
    float2 v; v.x = acc[i][0] + bias; v.y = acc[i][1] + bias;
    *(float2*)&y3[((size_t)b*128 + o)*512 + h0 + tx*2] = v;
  }
}

// per-channel sums of y3, y3^2, y3*xm (one block per channel, deterministic)
__global__ __launch_bounds__(256) void k_ystats(
    const float* __restrict__ y3, const float* __restrict__ xm,
    float* __restrict__ Sy, float* __restrict__ Syy, float* __restrict__ Sxy)
{
  const int c = blockIdx.x;
  const int t = threadIdx.x, wv = t >> 6, l = t & 63;
  float s=0.f, ss=0.f, sx=0.f;
  for(int i=0;i<32;++i){
    int idx = t + i*256;
    int b = idx >> 9, h = idx & 511;
    size_t off = ((size_t)b*128 + c)*512 + h;
    float v = y3[off], u = xm[off];
    s += v; ss += v*v; sx += v*u;
  }
  #pragma unroll
  for(int m=1;m<64;m<<=1){ s += __shfl_xor(s,m); ss += __shfl_xor(ss,m); sx += __shfl_xor(sx,m); }
  __shared__ float r1[4], r2[4], r3[4];
  if(l == 0){ r1[wv]=s; r2[wv]=ss; r3[wv]=sx; }
  __syncthreads();
  if(t == 0){
    Sy[c]  = r1[0]+r1[1]+r1[2]+r1[3];
    Syy[c] = r2[0]+r2[1]+r2[2]+r2[3];
    Sxy[c] = r3[0]+r3[1]+r3[2]+r3[3];
  }
}

// BN2 stats via decomposition: S2 = Sh + W*Sy ; Q2 = Qh + 2W*Sxy + W*Syy
__global__ __launch_bounds__(256) void k_bn2fin(
    const float* __restrict__ Sh, const float* __restrict__ Qh,
    const float* __restrict__ Sy, const float* __restrict__ Syy,
    const float* __restrict__ Sxy, const float* __restrict__ g2,
    const float* __restrict__ b2, float* __restrict__ s2, float* __restrict__ t2)
{
  int c = threadIdx.x; if(c >= 128) return;
  const double N = 524288.0;
  double S2 = (double)Sh[c] + 64.0*(double)Sy[c];
  double Q2 = (double)Qh[c] + 128.0*(double)Sxy[c] + 64.0*(double)Syy[c];
  double mu = S2/N, var = Q2/N - mu*mu;
  float sc = (float)((double)g2[c] / sqrt(var + 1e-5));
  s2[c] = sc;
  t2[c] = (float)((double)b2[c] - mu*(double)sc);
}

// out = silu(bn2(relu(bn1(conv)) + y3))
__global__ __launch_bounds__(256) void k_final(
    const unsigned short* __restrict__ craw, const float* __restrict__ s1,
    const float* __restrict__ t1, const float* __restrict__ y3,
    const float* __restrict__ s2, const float* __restrict__ t2,
    float* __restrict__ out)
{
  const int c = blockIdx.x, b = blockIdx.y;
  const int t = threadIdx.x, wv = t >> 6, l = t & 63;
  const float a1 = s1[c], c1 = t1[c], a2 = s2[c], c2 = t2[c];
  const size_t rb = ((size_t)b*128 + c)*512;
  const unsigned short* base = craw + rb*64;
  const float* yrow = y3 + rb;
  float* ob = out + rb*64;
  for(int it=0; it<16; ++it){
    int row = it*32 + wv*8 + (l >> 3);
    int w0 = (l & 7)*8;
    uint4 d = *(const uint4*)(base + (size_t)row*64 + w0);
    float yv = yrow[row];
    float r[8]; dec8(d, r);
    f32x4 o0, o1;
    #pragma unroll
    for(int j=0;j<8;++j){
      float h = a1*r[j] + c1; h = h > 0.f ? h : 0.f;
      float z = a2*(h + yv) + c2;
      float val = z * __builtin_amdgcn_rcpf(1.f + __expf(-z));
      if(j < 4) o0[j] = val; else o1[j-4] = val;
    }
    *(f32x4*)(ob + (size_t)row*64 + w0) = o0;
    *(f32x4*)(ob + (size_t)row*64 + w0 + 4) = o1;
  }
}

extern "C" void kernel_launch(void* const* d_in, const int* in_sizes, int n_in,
                              void* d_out, int out_size, void* d_ws, size_t ws_size,
                              hipStream_t stream)
{
  const float* x      = (const float*)d_in[0];
  const float* conv_w = (const float*)d_in[1];
  const float* bn1_g  = (const float*)d_in[2];
  const float* bn1_b  = (const float*)d_in[3];
  const float* g_w    = (const float*)d_in[4];
  const float* g_b    = (const float*)d_in[5];
  const float* out_w  = (const float*)d_in[6];
  const float* out_b  = (const float*)d_in[7];
  const float* bn2_g  = (const float*)d_in[8];
  const float* bn2_b  = (const float*)d_in[9];
  float* out = (float*)d_out;
  char* ws = (char*)d_ws;

  // ws layout (needs ~138.7 MB)
  float* sum_slots = (float*)(ws);            // 128*64
  float* sq_slots  = (float*)(ws + 32768);    // 128*64
  float* Sh        = (float*)(ws + 65536);    // 128
  float* Qh        = (float*)(ws + 66048);    // 128
  float* lnS       = (float*)(ws + 66560);    // 16
  float* lnQ       = (float*)(ws + 66624);    // 16  -- zero region ends at 66688
  float* s1        = (float*)(ws + 66688);
  float* t1        = (float*)(ws + 67200);
  float* ln_mu     = (float*)(ws + 67712);
  float* ln_rs     = (float*)(ws + 67776);
  float* Sy        = (float*)(ws + 67840);
  float* Syy       = (float*)(ws + 68352);
  float* Sxy       = (float*)(ws + 68864);
  float* s2        = (float*)(ws + 69376);
  float* t2        = (float*)(ws + 69888);
  unsigned short* wA = (unsigned short*)(ws + 70400);      // 147456 B
  float* y3        = (float*)(ws + 217856);                // 4 MB
  unsigned short* craw = (unsigned short*)(ws + 4412160);  // 134217728 B

  // intermediates that die before k_final live in d_out (268 MB) as scratch
  float* xm  = out;                 // 1M floats
  float* y1  = out + 2*(1u<<20);
  float* y2t = out + 3*(1u<<20);
  float* f   = out + 4*(1u<<20);    // 4M floats
  unsigned short* xbf = (unsigned short*)((char*)out + (size_t)64*1024*1024); // 67 MB, dies before k_final

  hipMemsetAsync(ws, 0, 66688, stream);
  hipLaunchKernelGGL(k_prep,   dim3(288),      dim3(256), 0, stream, conv_w, wA);
  hipLaunchKernelGGL(k_xbf,    dim3(512,16),   dim3(256), 0, stream, x, xbf);
  hipLaunchKernelGGL(k_conv,   dim3(128,16),   dim3(256), 0, stream, xbf, wA, craw, sum_slots, sq_slots);
  hipLaunchKernelGGL(k_bn1fin, dim3(1),        dim3(128), 0, stream, sum_slots, sq_slots, bn1_g, bn1_b, s1, t1);
  hipLaunchKernelGGL(k_passB,  dim3(128,16),   dim3(256), 0, stream, craw, s1, t1, xm, Sh, Qh, lnS, lnQ);
  hipLaunchKernelGGL(k_lnfin,  dim3(1),        dim3(64),  0, stream, lnS, lnQ, ln_mu, ln_rs);
  hipLaunchKernelGGL(k_f,      dim3(8,8,16),   dim3(256), 0, stream, xm, ln_mu, ln_rs, f);
  hipLaunchKernelGGL(k_sm,     dim3(2048),     dim3(256), 0, stream, f);
  hipLaunchKernelGGL(k_y1,     dim3(8,16),     dim3(256), 0, stream, xm, ln_mu, ln_rs, g_w, g_b, y1);
  hipLaunchKernelGGL(k_y2,     dim3(16,16),    dim3(256), 0, stream, f, y1, y2t);
  hipLaunchKernelGGL(k_y3,     dim3(16,16),    dim3(256), 0, stream, y2t, out_w, out_b, y3);
  hipLaunchKernelGGL(k_ystats, dim3(128),      dim3(256), 0, stream, y3, xm, Sy, Syy, Sxy);
  hipLaunchKernelGGL(k_bn2fin, dim3(1),        dim3(128), 0, stream, Sh, Qh, Sy, Syy, Sxy, bn2_g, bn2_b, s2, t2);
  hipLaunchKernelGGL(k_final,  dim3(128,16),   dim3(256), 0, stream, craw, s1, t1, y3, s2, t2, out);
}

// Round 3
// 739.909 us; speedup vs baseline: 1.1731x; 1.0792x over previous
//
#include <hip/hip_runtime.h>
#include <stdint.h>

typedef __attribute__((ext_vector_type(8))) short short8;
typedef __attribute__((ext_vector_type(4))) float f32x4;

typedef const __attribute__((address_space(1))) unsigned int* gas_u32p;
typedef __attribute__((address_space(3))) unsigned int* las_u32p;

__device__ __forceinline__ unsigned short f2bf(float f){
  union{float f; unsigned u;} v; v.f = f;
  unsigned r = v.u + 0x7FFFu + ((v.u >> 16) & 1u);
  return (unsigned short)(r >> 16);
}
__device__ __forceinline__ void dec8(uint4 d, float* r){
  union{unsigned a; float f;} t;
  t.a = (d.x & 0xFFFFu) << 16; r[0]=t.f; t.a = d.x & 0xFFFF0000u; r[1]=t.f;
  t.a = (d.y & 0xFFFFu) << 16; r[2]=t.f; t.a = d.y & 0xFFFF0000u; r[3]=t.f;
  t.a = (d.z & 0xFFFFu) << 16; r[4]=t.f; t.a = d.z & 0xFFFF0000u; r[5]=t.f;
  t.a = (d.w & 0xFFFFu) << 16; r[6]=t.f; t.a = d.w & 0xFFFF0000u; r[7]=t.f;
}

// Pack conv_w [128][64][3][3] -> wA [ks=18][m=128][kk=32] bf16, k = (dh*3+dw)*64 + cin
__global__ __launch_bounds__(256) void k_prep(const float* __restrict__ cw,
                                              unsigned short* __restrict__ wA){
  int i = blockIdx.x*256 + threadIdx.x;
  if(i >= 18*128*32) return;
  int kk = i & 31, m = (i >> 5) & 127, ks = i >> 12;
  int k = ks*32 + kk;
  int pos = k >> 6, cin = k & 63;
  int dh = pos/3, dw = pos - dh*3;
  wA[i] = f2bf(cw[((m*64 + cin)*3 + dh)*3 + dw]);
}

// Transpose+convert x [b][c][h][w] fp32 -> xbf [b][h][w][c] bf16.
__global__ __launch_bounds__(256) void k_xbf(const float* __restrict__ x,
                                             unsigned short* __restrict__ xbf){
  const int h = blockIdx.x, b = blockIdx.y;
  __shared__ float L[64][65];
  const int t = threadIdx.x;
  #pragma unroll
  for(int i=0;i<4;++i){
    int idx = i*256 + t;            // 1024 float4 units
    int c = idx >> 4, w0 = (idx & 15) * 4;
    const float* p = x + (((size_t)b*64 + c)*512 + h)*64 + w0;
    float4 v = *(const float4*)p;
    L[c][w0] = v.x; L[c][w0+1] = v.y; L[c][w0+2] = v.z; L[c][w0+3] = v.w;
  }
  __syncthreads();
  unsigned short* dst = xbf + (((size_t)b*512 + h) << 12);
  #pragma unroll
  for(int i=0;i<8;++i){
    int idx = i*256 + t;            // 2048 u32 units
    int w = idx >> 5, c2 = (idx & 31)*2;
    unsigned pk = (unsigned)f2bf(L[c2][w]) | ((unsigned)f2bf(L[c2+1][w]) << 16);
    *(unsigned*)(dst + (w<<6) + c2) = pk;
  }
}

// Implicit-GEMM conv: block = (b, 4 output rows). Each wave owns one 64-w row:
// acc[8][4] (M=128 x N=64 per wave, K=576, 576 MFMA/wave). LDS: 6 halo rows,
// linear, XOR swizzle folded into global source + precomputed P[nt][dw] read bases.
__global__ __launch_bounds__(256, 2) void k_conv(
    const unsigned short* __restrict__ xbf, const unsigned short* __restrict__ wA,
    unsigned short* __restrict__ craw, float* __restrict__ sum_slots,
    float* __restrict__ sq_slots)
{
  const int b = blockIdx.y;
  const int bx = blockIdx.x;                 // 0..127
  const int hx = (bx & 7)*16 + (bx >> 3);    // XCD swizzle, bijective (128 = 8*16)
  const int h0 = hx * 4;
  __shared__ __align__(16) unsigned short xs[6*4096];   // 48 KB linear
  __shared__ float red[2][128];
  const int t = threadIdx.x;
  const int lane = t & 63, wv = t >> 6;
  // stage 6 halo rows (rows h0-1 .. h0+4), 8 KB each via global_load_lds dwordx4
  for(int r = wv; r < 6; r += 4){
    int hin = h0 - 1 + r;
    hin = hin < 0 ? 1 : (hin > 511 ? 510 : hin);   // reflect pad
    const unsigned short* rsrc = xbf + (((size_t)b*512 + hin) << 12);
    unsigned short* ldsrow = &xs[r*4096];
    #pragma unroll
    for(int it=0; it<8; ++it){
      int o = it*1024 + lane*16;                   // byte offset within 8 KB row
      int w = o >> 7;
      int q = o & 127;
      int so = (w << 7) + (q ^ (((w >> 1) & 7) << 4));   // pre-swizzled source
      __builtin_amdgcn_global_load_lds(
          (gas_u32p)(const void*)((const char*)rsrc + so),
          (las_u32p)(void*)(ldsrow + it*512), 16, 0, 0);
    }
  }
  const int r15 = lane & 15, quad = lane >> 4;
  // Precompute swizzled LDS byte-offsets: nt covers w = (nt>>1)*32 + 2*r15 + (nt&1)
  int P[4][3];
  #pragma unroll
  for(int nt=0;nt<4;++nt){
    int wn = (nt>>1)*32 + 2*r15 + (nt&1);
    #pragma unroll
    for(int dw=0;dw<3;++dw){
      int wi = wn + dw - 1;
      wi = wi < 0 ? 1 : (wi > 63 ? 62 : wi);     // reflect pad
      int s = ((wi >> 1) & 7) << 4;
      P[nt][dw] = (wi << 7) + ((quad*16) ^ (s & 0x30)) + (s & 0x40);
    }
  }
  f32x4 acc[8][4];
  #pragma unroll
  for(int mt=0;mt<8;++mt)
    #pragma unroll
    for(int nt=0;nt<4;++nt){ f32x4 z = {0.f,0.f,0.f,0.f}; acc[mt][nt] = z; }
  const unsigned short* wbase = wA + r15*32 + quad*8;
  __syncthreads();
  const char* xsb = (const char*)xs;
  #pragma unroll
  for(int ks=0; ks<18; ++ks){
    const int pos = ks >> 1;
    const int dh = pos/3, dw = pos - dh*3;
    const int kbit = (ks & 1) << 6;
    const int rowoff = (wv + dh)*8192;
    short8 a[8];
    const unsigned short* wk = wbase + ks*4096;
    #pragma unroll
    for(int mt=0;mt<8;++mt) a[mt] = *(const short8*)(wk + mt*512);
    short8 bfr[4];
    #pragma unroll
    for(int nt=0;nt<4;++nt)
      bfr[nt] = *(const short8*)(xsb + rowoff + (P[nt][dw] ^ kbit));
    #pragma unroll
    for(int mt=0;mt<8;++mt){
      #pragma unroll
      for(int nt=0;nt<4;++nt)
        acc[mt][nt] = __builtin_amdgcn_mfma_f32_16x16x32_bf16(a[mt], bfr[nt], acc[mt][nt], 0,0,0);
    }
  }
  // epilogue: D col=lane&15 -> w pairs (2*r15,2*r15+1) and (+32), row=quad*4+rg (m)
  {
    size_t obase = (((size_t)b*128)*512 + (size_t)(h0+wv))*64 + 2*r15;
    #pragma unroll
    for(int mt=0;mt<8;++mt){
      #pragma unroll
      for(int rg=0;rg<4;++rg){
        int co = mt*16 + quad*4 + rg;
        unsigned pk0 = (unsigned)f2bf(acc[mt][0][rg]) | ((unsigned)f2bf(acc[mt][1][rg]) << 16);
        unsigned pk1 = (unsigned)f2bf(acc[mt][2][rg]) | ((unsigned)f2bf(acc[mt][3][rg]) << 16);
        __builtin_nontemporal_store(pk0, (unsigned*)(craw + obase + (size_t)co*32768));
        __builtin_nontemporal_store(pk1, (unsigned*)(craw + obase + (size_t)co*32768 + 32));
      }
    }
  }
  // BN1 stats: per-cout sum/sumsq
  if(t < 128){ red[0][t] = 0.f; red[1][t] = 0.f; }
  __syncthreads();
  #pragma unroll
  for(int mt=0;mt<8;++mt){
    #pragma unroll
    for(int rg=0;rg<4;++rg){
      float s = acc[mt][0][rg] + acc[mt][1][rg] + acc[mt][2][rg] + acc[mt][3][rg];
      float q = acc[mt][0][rg]*acc[mt][0][rg] + acc[mt][1][rg]*acc[mt][1][rg]
              + acc[mt][2][rg]*acc[mt][2][rg] + acc[mt][3][rg]*acc[mt][3][rg];
      #pragma unroll
      for(int m=1;m<16;m<<=1){ s += __shfl_xor(s, m); q += __shfl_xor(q, m); }
      if(r15 == 0){
        int co = mt*16 + quad*4 + rg;
        atomicAdd(&red[0][co], s);
        atomicAdd(&red[1][co], q);
      }
    }
  }
  __syncthreads();
  if(t < 128){
    int slot = bx & 63;
    atomicAdd(&sum_slots[t*64 + slot], red[0][t]);
    atomicAdd(&sq_slots[t*64 + slot], red[1][t]);
  }
}

__global__ __launch_bounds__(256) void k_bn1fin(
    const float* __restrict__ sum_slots, const float* __restrict__ sq_slots,
    const float* __restrict__ g1, const float* __restrict__ b1,
    float* __restrict__ s1, float* __restrict__ t1)
{
  int c = threadIdx.x; if(c >= 128) return;
  double S = 0.0, Q = 0.0;
  for(int s=0;s<64;++s){ S += (double)sum_slots[c*64+s]; Q += (double)sq_slots[c*64+s]; }
  const double N = 524288.0;
  double mu = S/N, var = Q/N - mu*mu;
  float sc = (float)((double)g1[c] / sqrt(var + 1e-5));
  s1[c] = sc;
  t1[c] = (float)((double)b1[c] - mu*(double)sc);
}

// read conv_raw, h=relu(bn1), emit xm=mean_w(h), S_h/Q_h per channel, LN partials per batch
__global__ __launch_bounds__(256) void k_passB(
    const unsigned short* __restrict__ craw, const float* __restrict__ s1,
    const float* __restrict__ t1, float* __restrict__ xm,
    float* __restrict__ Sh, float* __restrict__ Qh,
    float* __restrict__ lnS, float* __restrict__ lnQ)
{
  const int c = blockIdx.x, b = blockIdx.y;
  const int t = threadIdx.x, wv = t >> 6, l = t & 63;
  const float sc = s1[c], sf = t1[c];
  const unsigned short* base = craw + (((size_t)b*128 + c)*512)*64;
  float* xrow = xm + ((size_t)b*128 + c)*512;
  float sa = 0.f, qa = 0.f, la = 0.f;
  for(int it=0; it<16; ++it){
    int row = it*32 + wv*8 + (l >> 3);
    int w0 = (l & 7)*8;
    uint4 d = *(const uint4*)(base + (size_t)row*64 + w0);
    float r[8]; dec8(d, r);
    float tot = 0.f;
    #pragma unroll
    for(int j=0;j<8;++j){
      float v = sc*r[j] + sf;
      v = v > 0.f ? v : 0.f;
      tot += v; sa += v; qa += v*v;
    }
    tot += __shfl_xor(tot, 1); tot += __shfl_xor(tot, 2); tot += __shfl_xor(tot, 4);
    if((l & 7) == 0){
      float mv = tot * (1.f/64.f);
      xrow[row] = mv;
      la += mv*mv;
    }
  }
  #pragma unroll
  for(int m=1;m<64;m<<=1){
    sa += __shfl_xor(sa, m); qa += __shfl_xor(qa, m); la += __shfl_xor(la, m);
  }
  __shared__ float rs[4], rq[4], rl[4];
  if(l == 0){ rs[wv]=sa; rq[wv]=qa; rl[wv]=la; }
  __syncthreads();
  if(t == 0){
    float S = rs[0]+rs[1]+rs[2]+rs[3];
    float Q = rq[0]+rq[1]+rq[2]+rq[3];
    float L = rl[0]+rl[1]+rl[2]+rl[3];
    atomicAdd(&Sh[c], S);
    atomicAdd(&Qh[c], Q);
    atomicAdd(&lnS[b], S * (1.f/64.f));
    atomicAdd(&lnQ[b], L);
  }
}

__global__ __launch_bounds__(256) void k_lnfin(
    const float* __restrict__ lnS, const float* __restrict__ lnQ,
    float* __restrict__ ln_mu, float* __restrict__ ln_rs)
{
  int b = threadIdx.x; if(b >= 16) return;
  double mu = (double)lnS[b] / 65536.0;
  double var = (double)lnQ[b] / 65536.0 - mu*mu;
  ln_mu[b] = (float)mu;
  ln_rs[b] = (float)(1.0 / sqrt(var + 1e-5));
}

// y1[b,m,k] = sum_c g_w[m,c]*xn[b,c,k] + g_b[m]; xn on the fly from xm
__global__ __launch_bounds__(256) void k_y1(
    const float* __restrict__ xm, const float* __restrict__ ln_mu,
    const float* __restrict__ ln_rs, const float* __restrict__ gw,
    const float* __restrict__ gb, float* __restrict__ y1)
{
  const int kt = blockIdx.x, b = blockIdx.y;
  __shared__ __align__(16) float GT[128*132];   // [c][o], pad 132
  __shared__ __align__(16) float XN[128*68];    // [c][k], pad 68
  const int t = threadIdx.x;
  const int k0 = kt*64;
  const float mu = ln_mu[b], rs = ln_rs[b];
  // stage g_w transposed: coalesced f4 reads along c, scatter writes to LDS
  #pragma unroll
  for(int i=0;i<16;++i){
    int idx = t + i*256;                 // 4096 f4 units
    int c4 = (idx & 31)*4, o = idx >> 5;
    float4 v = *(const float4*)&gw[o*128 + c4];
    GT[(c4+0)*132 + o] = v.x; GT[(c4+1)*132 + o] = v.y;
    GT[(c4+2)*132 + o] = v.z; GT[(c4+3)*132 + o] = v.w;
  }
  #pragma unroll
  for(int i=0;i<8;++i){
    int idx = t + i*256;                 // 2048 f4 units
    int kk4 = (idx & 15)*4, c = idx >> 4;
    float4 v = *(const float4*)&xm[((size_t)b*128 + c)*512 + k0 + kk4];
    XN[c*68 + kk4 + 0] = (v.x - mu)*rs; XN[c*68 + kk4 + 1] = (v.y - mu)*rs;
    XN[c*68 + kk4 + 2] = (v.z - mu)*rs; XN[c*68 + kk4 + 3] = (v.w - mu)*rs;
  }
  __syncthreads();
  const int tx = t & 15, ty = t >> 4;
  float acc[8][4] = {{0}};
  for(int c=0;c<128;++c){
    f32x4 a0 = *(const f32x4*)&GT[c*132 + ty*8];
    f32x4 a1 = *(const f32x4*)&GT[c*132 + ty*8 + 4];
    f32x4 bv = *(const f32x4*)&XN[c*68 + tx*4];
    #pragma unroll
    for(int j=0;j<4;++j){
      #pragma unroll
      for(int i=0;i<4;++i){ acc[i][j] += a0[i]*bv[j]; acc[i+4][j] += a1[i]*bv[j]; }
    }
  }
  #pragma unroll
  for(int i=0;i<8;++i){
    int m = ty*8 + i;
    float bias = gb[m];
    f32x4 o;
    #pragma unroll
    for(int j=0;j<4;++j) o[j] = acc[i][j] + bias;
    *(f32x4*)&y1[((size_t)b*128 + m)*512 + k0 + tx*4] = o;
  }
}

// Fused attention: replaces k_f, k_sm, k_y2, k_y3, k_ystats.
// Block = (ht, b): 32 h-rows. S[32][512] in LDS, two-pass softmax, P*y1^T, out_w*y2.
// Emits y3 + BN2 stat slot-atomics.
__global__ __launch_bounds__(256) void k_att(
    const float* __restrict__ xm, const float* __restrict__ ln_mu,
    const float* __restrict__ ln_rs, const float* __restrict__ y1,
    const float* __restrict__ ow, const float* __restrict__ obv,
    float* __restrict__ y3,
    float* __restrict__ SyS, float* __restrict__ SyyS, float* __restrict__ SxyS)
{
  const int ht = blockIdx.x, b = blockIdx.y;
  const int h0 = ht*32;
  const int SP = 528;                       // S row stride (mult of 4, %32==16)
  __shared__ __align__(16) float S[32*528]; // 67.6 KB; also reused as OWT[128][132]
  __shared__ __align__(16) float XH[128*32];// 16.4 KB
  __shared__ __align__(16) float BUF[8704]; // 34.8 KB: XK[128][68] / Y1T[64][132] / Y2L[32][131]
  const int t = threadIdx.x;
  const int tx = t & 15, ty = t >> 4;
  const int lane = t & 63, wv = t >> 6;
  const float mu = ln_mu[b], rs = ln_rs[b];
  const float* xb = xm + (size_t)b*128*512;
  // stage XH[c][hh] = xn[b,c,h0+hh]
  #pragma unroll
  for(int i=0;i<4;++i){
    int idx = t + i*256;                   // 1024 f4
    int hh4 = (idx & 7)*4, c = idx >> 3;
    float4 v = *(const float4*)&xb[(size_t)c*512 + h0 + hh4];
    XH[c*32 + hh4 + 0] = (v.x - mu)*rs; XH[c*32 + hh4 + 1] = (v.y - mu)*rs;
    XH[c*32 + hh4 + 2] = (v.z - mu)*rs; XH[c*32 + hh4 + 3] = (v.w - mu)*rs;
  }
  // pass 1: S[h][k] = xn_h . xn_k * 1/sqrt(128)
  const float sscale = 0.088388347648318447f;
  for(int kt=0;kt<8;++kt){
    int k0 = kt*64;
    #pragma unroll
    for(int i=0;i<8;++i){
      int idx = t + i*256;                 // 2048 f4
      int kk4 = (idx & 15)*4, c = idx >> 4;
      float4 v = *(const float4*)&xb[(size_t)c*512 + k0 + kk4];
      BUF[c*68 + kk4 + 0] = (v.x - mu)*rs; BUF[c*68 + kk4 + 1] = (v.y - mu)*rs;
      BUF[c*68 + kk4 + 2] = (v.z - mu)*rs; BUF[c*68 + kk4 + 3] = (v.w - mu)*rs;
    }
    __syncthreads();
    float acc[2][4] = {{0}};
    for(int c=0;c<128;++c){
      float a0 = XH[c*32 + ty*2];
      float a1 = XH[c*32 + ty*2 + 1];
      f32x4 bv = *(const f32x4*)&BUF[c*68 + tx*4];
      #pragma unroll
      for(int j=0;j<4;++j){ acc[0][j] += a0*bv[j]; acc[1][j] += a1*bv[j]; }
    }
    #pragma unroll
    for(int i=0;i<2;++i){
      f32x4 o;
      #pragma unroll
      for(int j=0;j<4;++j) o[j] = acc[i][j]*sscale;
      *(f32x4*)&S[(ty*2+i)*SP + k0 + tx*4] = o;
    }
    __syncthreads();
  }
  // pass 2: softmax rows (wave wv owns rows wv*8..wv*8+7)
  #pragma unroll
  for(int rr=0;rr<8;++rr){
    int row = wv*8 + rr;
    float* rowp = &S[row*SP];
    f32x4 v0 = *(const f32x4*)&rowp[lane*8];
    f32x4 v1 = *(const f32x4*)&rowp[lane*8 + 4];
    float mx = v0[0];
    #pragma unroll
    for(int j=1;j<4;++j) mx = fmaxf(mx, v0[j]);
    #pragma unroll
    for(int j=0;j<4;++j) mx = fmaxf(mx, v1[j]);
    #pragma unroll
    for(int m=1;m<64;m<<=1) mx = fmaxf(mx, __shfl_xor(mx, m));
    float sum = 0.f;
    #pragma unroll
    for(int j=0;j<4;++j){ v0[j] = __expf(v0[j]-mx); sum += v0[j]; }
    #pragma unroll
    for(int j=0;j<4;++j){ v1[j] = __expf(v1[j]-mx); sum += v1[j]; }
    #pragma unroll
    for(int m=1;m<64;m<<=1) sum += __shfl_xor(sum, m);
    float inv = 1.f / sum;
    #pragma unroll
    for(int j=0;j<4;++j){ v0[j] *= inv; v1[j] *= inv; }
    *(f32x4*)&rowp[lane*8] = v0;
    *(f32x4*)&rowp[lane*8+4] = v1;
  }
  __syncthreads();
  // pass 3: y2[h][m] = sum_k P[h][k] * y1[b,m,k]
  float y2a[2][8] = {{0}};
  for(int kt=0;kt<8;++kt){
    int k0 = kt*64;
    #pragma unroll
    for(int i=0;i<8;++i){
      int idx = t + i*256;                 // 2048 f4
      int kk4 = (idx & 15)*4, m = idx >> 4;
      float4 v = *(const float4*)&y1[((size_t)b*128 + m)*512 + k0 + kk4];
      BUF[(kk4+0)*132 + m] = v.x; BUF[(kk4+1)*132 + m] = v.y;
      BUF[(kk4+2)*132 + m] = v.z; BUF[(kk4+3)*132 + m] = v.w;
    }
    __syncthreads();
    for(int kk=0;kk<64;++kk){
      float a0 = S[(ty*2)*SP + k0 + kk];
      float a1 = S[(ty*2+1)*SP + k0 + kk];
      f32x4 b0 = *(const f32x4*)&BUF[kk*132 + tx*8];
      f32x4 b1 = *(const f32x4*)&BUF[kk*132 + tx*8 + 4];
      #pragma unroll
      for(int j=0;j<4;++j){
        y2a[0][j]   += a0*b0[j]; y2a[1][j]   += a1*b0[j];
        y2a[0][j+4] += a0*b1[j]; y2a[1][j+4] += a1*b1[j];
      }
    }
    __syncthreads();
  }
  // spill y2 to LDS as Y2L[h][m] (pad 131), stage out_w transposed OWT[m][o] into S region
  #pragma unroll
  for(int i=0;i<2;++i)
    #pragma unroll
    for(int j=0;j<8;++j)
      BUF[(ty*2+i)*131 + tx*8 + j] = y2a[i][j];
  float* OWT = S;                          // 128*132 = 16896 floats, fits exactly
  #pragma unroll
  for(int i=0;i<16;++i){
    int idx = t + i*256;                   // 4096 f4
    int m4 = (idx & 31)*4, o = idx >> 5;
    float4 v = *(const float4*)&ow[o*128 + m4];
    OWT[(m4+0)*132 + o] = v.x; OWT[(m4+1)*132 + o] = v.y;
    OWT[(m4+2)*132 + o] = v.z; OWT[(m4+3)*132 + o] = v.w;
  }
  __syncthreads();
  // pass 4: y3[o][h] = sum_m ow[o][m]*y2[h][m] + bias; o = ty*8+j, h = h0 + tx*2 + i
  float a2[2][8] = {{0}};
  for(int m=0;m<128;++m){
    f32x4 w0 = *(const f32x4*)&OWT[m*132 + ty*8];
    f32x4 w1 = *(const f32x4*)&OWT[m*132 + ty*8 + 4];
    float h0v = BUF[(tx*2)*131 + m];
    float h1v = BUF[(tx*2+1)*131 + m];
    #pragma unroll
    for(int j=0;j<4;++j){
      a2[0][j]   += w0[j]*h0v; a2[1][j]   += w0[j]*h1v;
      a2[0][j+4] += w1[j]*h0v; a2[1][j+4] += w1[j]*h1v;
    }
  }
  const int slot = ((ht<<4) | b) & 31;
  #pragma unroll
  for(int j=0;j<8;++j){
    int o = ty*8 + j;
    float bias = obv[o];
    float v0 = a2[0][j] + bias;
    float v1 = a2[1][j] + bias;
    size_t off = ((size_t)b*128 + o)*512 + h0 + tx*2;
    float2 st; st.x = v0; st.y = v1;
    *(float2*)&y3[off] = st;
    float2 xv = *(const float2*)&xm[off];
    float sy_ = v0 + v1;
    float syy_ = v0*v0 + v1*v1;
    float sxy_ = v0*xv.x + v1*xv.y;
    #pragma unroll
    for(int m=1;m<16;m<<=1){
      sy_ += __shfl_xor(sy_, m); syy_ += __shfl_xor(syy_, m); sxy_ += __shfl_xor(sxy_, m);
    }
    if(tx == 0){
      atomicAdd(&SyS[o*32 + slot], sy_);
      atomicAdd(&SyyS[o*32 + slot], syy_);
      atomicAdd(&SxyS[o*32 + slot], sxy_);
    }
  }
}

// BN2 stats via decomposition: S2 = Sh + W*Sy ; Q2 = Qh + 2W*Sxy + W*Syy
__global__ __launch_bounds__(256) void k_bn2fin(
    const float* __restrict__ Sh, const float* __restrict__ Qh,
    const float* __restrict__ SyS, const float* __restrict__ SyyS,
    const float* __restrict__ SxyS, const float* __restrict__ g2,
    const float* __restrict__ b2, float* __restrict__ s2, float* __restrict__ t2)
{
  int c = threadIdx.x; if(c >= 128) return;
  double Sy = 0.0, Syy = 0.0, Sxy = 0.0;
  for(int s=0;s<32;++s){
    Sy  += (double)SyS[c*32+s];
    Syy += (double)SyyS[c*32+s];
    Sxy += (double)SxyS[c*32+s];
  }
  const double N = 524288.0;
  double S2 = (double)Sh[c] + 64.0*Sy;
  double Q2 = (double)Qh[c] + 128.0*Sxy + 64.0*Syy;
  double mu = S2/N, var = Q2/N - mu*mu;
  float sc = (float)((double)g2[c] / sqrt(var + 1e-5));
  s2[c] = sc;
  t2[c] = (float)((double)b2[c] - mu*(double)sc);
}

// out = silu(bn2(relu(bn1(conv)) + y3))
__global__ __launch_bounds__(256) void k_final(
    const unsigned short* __restrict__ craw, const float* __restrict__ s1,
    const float* __restrict__ t1, const float* __restrict__ y3,
    const float* __restrict__ s2, const float* __restrict__ t2,
    float* __restrict__ out)
{
  const int c = blockIdx.x, b = blockIdx.y;
  const int t = threadIdx.x, wv = t >> 6, l = t & 63;
  const float a1 = s1[c], c1 = t1[c], a2 = s2[c], c2 = t2[c];
  const size_t rb = ((size_t)b*128 + c)*512;
  const unsigned short* base = craw + rb*64;
  const float* yrow = y3 + rb;
  float* ob = out + rb*64;
  for(int it=0; it<16; ++it){
    int row = it*32 + wv*8 + (l >> 3);
    int w0 = (l & 7)*8;
    uint4 d = *(const uint4*)(base + (size_t)row*64 + w0);
    float yv = yrow[row];
    float r[8]; dec8(d, r);
    f32x4 o0, o1;
    #pragma unroll
    for(int j=0;j<8;++j){
      float h = a1*r[j] + c1; h = h > 0.f ? h : 0.f;
      float z = a2*(h + yv) + c2;
      float val = z * __builtin_amdgcn_rcpf(1.f + __expf(-z));
      if(j < 4) o0[j] = val; else o1[j-4] = val;
    }
    *(f32x4*)(ob + (size_t)row*64 + w0) = o0;
    *(f32x4*)(ob + (size_t)row*64 + w0 + 4) = o1;
  }
}

extern "C" void kernel_launch(void* const* d_in, const int* in_sizes, int n_in,
                              void* d_out, int out_size, void* d_ws, size_t ws_size,
                              hipStream_t stream)
{
  const float* x      = (const float*)d_in[0];
  const float* conv_w = (const float*)d_in[1];
  const float* bn1_g  = (const float*)d_in[2];
  const float* bn1_b  = (const float*)d_in[3];
  const float* g_w    = (const float*)d_in[4];
  const float* g_b    = (const float*)d_in[5];
  const float* out_w  = (const float*)d_in[6];
  const float* out_b  = (const float*)d_in[7];
  const float* bn2_g  = (const float*)d_in[8];
  const float* bn2_b  = (const float*)d_in[9];
  float* out = (float*)d_out;
  char* ws = (char*)d_ws;

  // ws layout (same footprint as before, ~138.6 MB)
  float* sum_slots = (float*)(ws);            // 128*64 (conv); reused by att stats
  float* sq_slots  = (float*)(ws + 32768);    // 128*64
  float* SyS       = (float*)(ws);            // 128*32 (after 2nd memset)
  float* SyyS      = (float*)(ws + 16384);    // 128*32
  float* SxyS      = (float*)(ws + 32768);    // 128*32 (ends 49152)
  float* Sh        = (float*)(ws + 65536);    // 128
  float* Qh        = (float*)(ws + 66048);    // 128
  float* lnS       = (float*)(ws + 66560);    // 16
  float* lnQ       = (float*)(ws + 66624);    // 16  -- zero region ends at 66688
  float* s1        = (float*)(ws + 66688);
  float* t1        = (float*)(ws + 67200);
  float* ln_mu     = (float*)(ws + 67712);
  float* ln_rs     = (float*)(ws + 67776);
  float* s2        = (float*)(ws + 67840);
  float* t2        = (float*)(ws + 68352);
  unsigned short* wA = (unsigned short*)(ws + 70400);      // 147456 B
  float* y3        = (float*)(ws + 217856);                // 4 MB
  unsigned short* craw = (unsigned short*)(ws + 4412160);  // 134217728 B

  // intermediates that die before k_final live in d_out (268 MB) as scratch
  float* xm  = out;                 // 1M floats
  float* y1  = out + 2*(1u<<20);
  unsigned short* xbf = (unsigned short*)((char*)out + (size_t)64*1024*1024); // 67 MB

  hipMemsetAsync(ws, 0, 66688, stream);
  hipLaunchKernelGGL(k_prep,   dim3(288),      dim3(256), 0, stream, conv_w, wA);
  hipLaunchKernelGGL(k_xbf,    dim3(512,16),   dim3(256), 0, stream, x, xbf);
  hipLaunchKernelGGL(k_conv,   dim3(128,16),   dim3(256), 0, stream, xbf, wA, craw, sum_slots, sq_slots);
  hipLaunchKernelGGL(k_bn1fin, dim3(1),        dim3(128), 0, stream, sum_slots, sq_slots, bn1_g, bn1_b, s1, t1);
  hipMemsetAsync(ws, 0, 49152, stream);   // clear att stat slots (conv slots consumed)
  hipLaunchKernelGGL(k_passB,  dim3(128,16),   dim3(256), 0, stream, craw, s1, t1, xm, Sh, Qh, lnS, lnQ);
  hipLaunchKernelGGL(k_lnfin,  dim3(1),        dim3(64),  0, stream, lnS, lnQ, ln_mu, ln_rs);
  hipLaunchKernelGGL(k_y1,     dim3(8,16),     dim3(256), 0, stream, xm, ln_mu, ln_rs, g_w, g_b, y1);
  hipLaunchKernelGGL(k_att,    dim3(16,16),    dim3(256), 0, stream, xm, ln_mu, ln_rs, y1, out_w, out_b, y3, SyS, SyyS, SxyS);
  hipLaunchKernelGGL(k_bn2fin, dim3(1),        dim3(128), 0, stream, Sh, Qh, SyS, SyyS, SxyS, bn2_g, bn2_b, s2, t2);
  hipLaunchKernelGGL(k_final,  dim3(128,16),   dim3(256), 0, stream, craw, s1, t1, y3, s2, t2, out);
}

// Round 5
// 694.244 us; speedup vs baseline: 1.2503x; 1.0658x over previous
//
#include <hip/hip_runtime.h>
#include <stdint.h>

typedef __attribute__((ext_vector_type(8))) short short8;
typedef __attribute__((ext_vector_type(4))) float f32x4;
typedef __attribute__((ext_vector_type(4))) unsigned int u32x4;

typedef const __attribute__((address_space(1))) unsigned int* gas_u32p;
typedef __attribute__((address_space(3))) unsigned int* las_u32p;

__device__ __forceinline__ unsigned short f2bf(float f){
  union{float f; unsigned u;} v; v.f = f;
  unsigned r = v.u + 0x7FFFu + ((v.u >> 16) & 1u);
  return (unsigned short)(r >> 16);
}
__device__ __forceinline__ void dec8(u32x4 d, float* r){
  union{unsigned a; float f;} t;
  t.a = (d[0] & 0xFFFFu) << 16; r[0]=t.f; t.a = d[0] & 0xFFFF0000u; r[1]=t.f;
  t.a = (d[1] & 0xFFFFu) << 16; r[2]=t.f; t.a = d[1] & 0xFFFF0000u; r[3]=t.f;
  t.a = (d[2] & 0xFFFFu) << 16; r[4]=t.f; t.a = d[2] & 0xFFFF0000u; r[5]=t.f;
  t.a = (d[3] & 0xFFFFu) << 16; r[6]=t.f; t.a = d[3] & 0xFFFF0000u; r[7]=t.f;
}

// Pack conv_w [128][64][3][3] -> wA [ks=18][m=128][kk=32] bf16, k = (dh*3+dw)*64 + cin
__global__ __launch_bounds__(256) void k_prep(const float* __restrict__ cw,
                                              unsigned short* __restrict__ wA){
  int i = blockIdx.x*256 + threadIdx.x;
  if(i >= 18*128*32) return;
  int kk = i & 31, m = (i >> 5) & 127, ks = i >> 12;
  int k = ks*32 + kk;
  int pos = k >> 6, cin = k & 63;
  int dh = pos/3, dw = pos - dh*3;
  wA[i] = f2bf(cw[((m*64 + cin)*3 + dh)*3 + dw]);
}

// Transpose+convert x [b][c][h][w] fp32 -> xbf [b][h][w][c] bf16.
__global__ __launch_bounds__(256) void k_xbf(const float* __restrict__ x,
                                             unsigned short* __restrict__ xbf){
  const int h = blockIdx.x, b = blockIdx.y;
  __shared__ float L[64][65];
  const int t = threadIdx.x;
  #pragma unroll
  for(int i=0;i<4;++i){
    int idx = i*256 + t;            // 1024 float4 units
    int c = idx >> 4, w0 = (idx & 15) * 4;
    const float* p = x + (((size_t)b*64 + c)*512 + h)*64 + w0;
    f32x4 v = __builtin_nontemporal_load((const f32x4*)p);
    L[c][w0] = v[0]; L[c][w0+1] = v[1]; L[c][w0+2] = v[2]; L[c][w0+3] = v[3];
  }
  __syncthreads();
  unsigned short* dst = xbf + (((size_t)b*512 + h) << 12);
  #pragma unroll
  for(int i=0;i<8;++i){
    int idx = i*256 + t;            // 2048 u32 units
    int w = idx >> 5, c2 = (idx & 31)*2;
    unsigned pk = (unsigned)f2bf(L[c2][w]) | ((unsigned)f2bf(L[c2+1][w]) << 16);
    *(unsigned*)(dst + (w<<6) + c2) = pk;
  }
}

// Implicit-GEMM conv: block = (b, 4 output rows). Each wave owns one 64-w row:
// acc[8][4] (M=128 x N=64 per wave, K=576, 576 MFMA/wave).
// x staged once in LDS (XOR-swizzled source); weights staged per-K-step into a
// double-buffered LDS tile via global_load_lds (2-phase pipeline, T3-minimum):
//   iter ks: [stage wbuf[next]] [ds_read A,B] [MFMA w/ setprio] [barrier]
__global__ __launch_bounds__(256, 2) void k_conv(
    const unsigned short* __restrict__ xbf, const unsigned short* __restrict__ wA,
    unsigned short* __restrict__ craw, float* __restrict__ sum_slots,
    float* __restrict__ sq_slots)
{
  const int b = blockIdx.y;
  const int bx = blockIdx.x;                 // 0..127
  const int hx = (bx & 7)*16 + (bx >> 3);    // XCD swizzle, bijective (128 = 8*16)
  const int h0 = hx * 4;
  __shared__ __align__(16) unsigned short xs[6*4096];     // 48 KB linear
  __shared__ __align__(16) unsigned short wbuf[2][4096];  // 16 KB dbuf
  __shared__ float red[2][128];
  const int t = threadIdx.x;
  const int lane = t & 63, wv = t >> 6;
  // stage 6 halo rows (rows h0-1 .. h0+4), 8 KB each via global_load_lds dwordx4
  for(int r = wv; r < 6; r += 4){
    int hin = h0 - 1 + r;
    hin = hin < 0 ? 1 : (hin > 511 ? 510 : hin);   // reflect pad
    const unsigned short* rsrc = xbf + (((size_t)b*512 + hin) << 12);
    unsigned short* ldsrow = &xs[r*4096];
    #pragma unroll
    for(int it=0; it<8; ++it){
      int o = it*1024 + lane*16;                   // byte offset within 8 KB row
      int w = o >> 7;
      int q = o & 127;
      int so = (w << 7) + (q ^ (((w >> 1) & 7) << 4));   // pre-swizzled source
      __builtin_amdgcn_global_load_lds(
          (gas_u32p)(const void*)((const char*)rsrc + so),
          (las_u32p)(void*)(ldsrow + it*512), 16, 0, 0);
    }
  }
  // stage wbuf[0] (ks=0 weight tile, 8 KB linear)
  #pragma unroll
  for(int j=0;j<2;++j){
    int off = j*2048 + wv*512;                     // shorts, wave-uniform
    __builtin_amdgcn_global_load_lds(
        (gas_u32p)(const void*)(wA + off + lane*8),
        (las_u32p)(void*)(&wbuf[0][off]), 16, 0, 0);
  }
  const int r15 = lane & 15, quad = lane >> 4;
  // Precompute swizzled LDS byte-offsets: nt covers w = (nt>>1)*32 + 2*r15 + (nt&1)
  int P[4][3];
  #pragma unroll
  for(int nt=0;nt<4;++nt){
    int wn = (nt>>1)*32 + 2*r15 + (nt&1);
    #pragma unroll
    for(int dw=0;dw<3;++dw){
      int wi = wn + dw - 1;
      wi = wi < 0 ? 1 : (wi > 63 ? 62 : wi);     // reflect pad
      int s = ((wi >> 1) & 7) << 4;
      P[nt][dw] = (wi << 7) + ((quad*16) ^ (s & 0x30)) + (s & 0x40);
    }
  }
  f32x4 acc[8][4];
  #pragma unroll
  for(int mt=0;mt<8;++mt)
    #pragma unroll
    for(int nt=0;nt<4;++nt){ f32x4 z = {0.f,0.f,0.f,0.f}; acc[mt][nt] = z; }
  __syncthreads();                                // xs + wbuf[0] ready
  const char* xsb = (const char*)xs;
  #pragma unroll
  for(int ks=0; ks<18; ++ks){
    if(ks < 17){                                  // stage next weight tile early
      const unsigned short* wsrc = wA + (ks+1)*4096;
      unsigned short* wdst = &wbuf[(ks+1)&1][0];
      #pragma unroll
      for(int j=0;j<2;++j){
        int off = j*2048 + wv*512;
        __builtin_amdgcn_global_load_lds(
            (gas_u32p)(const void*)(wsrc + off + lane*8),
            (las_u32p)(void*)(wdst + off), 16, 0, 0);
      }
    }
    const int pos = ks >> 1;
    const int dh = pos/3, dw = pos - dh*3;
    const int kbit = (ks & 1) << 6;
    const int rowoff = (wv + dh)*8192;
    const unsigned short* wk = &wbuf[ks&1][0];
    short8 a[8];
    #pragma unroll
    for(int mt=0;mt<8;++mt)
      a[mt] = *(const short8*)(wk + mt*512 + r15*32 + quad*8);
    short8 bfr[4];
    #pragma unroll
    for(int nt=0;nt<4;++nt)
      bfr[nt] = *(const short8*)(xsb + rowoff + (P[nt][dw] ^ kbit));
    __builtin_amdgcn_s_setprio(1);
    #pragma unroll
    for(int mt=0;mt<8;++mt){
      #pragma unroll
      for(int nt=0;nt<4;++nt)
        acc[mt][nt] = __builtin_amdgcn_mfma_f32_16x16x32_bf16(a[mt], bfr[nt], acc[mt][nt], 0,0,0);
    }
    __builtin_amdgcn_s_setprio(0);
    __syncthreads();                              // wbuf[next] complete, wbuf[cur] free
  }
  // epilogue: D col=lane&15 -> w pairs (2*r15,2*r15+1) and (+32), row=quad*4+rg (m)
  {
    size_t obase = (((size_t)b*128)*512 + (size_t)(h0+wv))*64 + 2*r15;
    #pragma unroll
    for(int mt=0;mt<8;++mt){
      #pragma unroll
      for(int rg=0;rg<4;++rg){
        int co = mt*16 + quad*4 + rg;
        unsigned pk0 = (unsigned)f2bf(acc[mt][0][rg]) | ((unsigned)f2bf(acc[mt][1][rg]) << 16);
        unsigned pk1 = (unsigned)f2bf(acc[mt][2][rg]) | ((unsigned)f2bf(acc[mt][3][rg]) << 16);
        __builtin_nontemporal_store(pk0, (unsigned*)(craw + obase + (size_t)co*32768));
        __builtin_nontemporal_store(pk1, (unsigned*)(craw + obase + (size_t)co*32768 + 32));
      }
    }
  }
  // BN1 stats: per-cout sum/sumsq
  if(t < 128){ red[0][t] = 0.f; red[1][t] = 0.f; }
  __syncthreads();
  #pragma unroll
  for(int mt=0;mt<8;++mt){
    #pragma unroll
    for(int rg=0;rg<4;++rg){
      float s = acc[mt][0][rg] + acc[mt][1][rg] + acc[mt][2][rg] + acc[mt][3][rg];
      float q = acc[mt][0][rg]*acc[mt][0][rg] + acc[mt][1][rg]*acc[mt][1][rg]
              + acc[mt][2][rg]*acc[mt][2][rg] + acc[mt][3][rg]*acc[mt][3][rg];
      #pragma unroll
      for(int m=1;m<16;m<<=1){ s += __shfl_xor(s, m); q += __shfl_xor(q, m); }
      if(r15 == 0){
        int co = mt*16 + quad*4 + rg;
        atomicAdd(&red[0][co], s);
        atomicAdd(&red[1][co], q);
      }
    }
  }
  __syncthreads();
  if(t < 128){
    int slot = bx & 63;
    atomicAdd(&sum_slots[t*64 + slot], red[0][t]);
    atomicAdd(&sq_slots[t*64 + slot], red[1][t]);
  }
}

__device__ __forceinline__ void bn1_coeff(
    const float* sum_slots, const float* sq_slots,
    const float* g1, const float* b1, int c, float* a1, float* c1)
{
  double S = 0.0, Q = 0.0;
  #pragma unroll
  for(int s=0;s<64;++s){ S += (double)sum_slots[c*64+s]; Q += (double)sq_slots[c*64+s]; }
  const double N = 524288.0;
  double mu = S/N, var = Q/N - mu*mu;
  float sc = (float)((double)g1[c] / sqrt(var + 1e-5));
  *a1 = sc;
  *c1 = (float)((double)b1[c] - mu*(double)sc);
}

// read conv_raw, h=relu(bn1), emit xm=mean_w(h), S_h/Q_h per channel, LN partials per batch
// (bn1fin folded: each block reduces the slots for its own channel)
__global__ __launch_bounds__(256) void k_passB(
    const unsigned short* __restrict__ craw,
    const float* __restrict__ sum_slots, const float* __restrict__ sq_slots,
    const float* __restrict__ g1, const float* __restrict__ b1,
    float* __restrict__ xm,
    float* __restrict__ Sh, float* __restrict__ Qh,
    float* __restrict__ lnS, float* __restrict__ lnQ)
{
  const int c = blockIdx.x, b = blockIdx.y;
  const int t = threadIdx.x, wv = t >> 6, l = t & 63;
  float sc, sf;
  bn1_coeff(sum_slots, sq_slots, g1, b1, c, &sc, &sf);
  const unsigned short* base = craw + (((size_t)b*128 + c)*512)*64;
  float* xrow = xm + ((size_t)b*128 + c)*512;
  float sa = 0.f, qa = 0.f, la = 0.f;
  for(int it=0; it<16; ++it){
    int row = it*32 + wv*8 + (l >> 3);
    int w0 = (l & 7)*8;
    u32x4 d = __builtin_nontemporal_load((const u32x4*)(base + (size_t)row*64 + w0));
    float r[8]; dec8(d, r);
    float tot = 0.f;
    #pragma unroll
    for(int j=0;j<8;++j){
      float v = sc*r[j] + sf;
      v = v > 0.f ? v : 0.f;
      tot += v; sa += v; qa += v*v;
    }
    tot += __shfl_xor(tot, 1); tot += __shfl_xor(tot, 2); tot += __shfl_xor(tot, 4);
    if((l & 7) == 0){
      float mv = tot * (1.f/64.f);
      xrow[row] = mv;
      la += mv*mv;
    }
  }
  #pragma unroll
  for(int m=1;m<64;m<<=1){
    sa += __shfl_xor(sa, m); qa += __shfl_xor(qa, m); la += __shfl_xor(la, m);
  }
  __shared__ float rs[4], rq[4], rl[4];
  if(l == 0){ rs[wv]=sa; rq[wv]=qa; rl[wv]=la; }
  __syncthreads();
  if(t == 0){
    float S = rs[0]+rs[1]+rs[2]+rs[3];
    float Q = rq[0]+rq[1]+rq[2]+rq[3];
    float L = rl[0]+rl[1]+rl[2]+rl[3];
    atomicAdd(&Sh[c], S);
    atomicAdd(&Qh[c], Q);
    atomicAdd(&lnS[b], S * (1.f/64.f));
    atomicAdd(&lnQ[b], L);
  }
}

__device__ __forceinline__ void ln_coeff(const float* lnS, const float* lnQ,
                                         int b, float* mu_o, float* rs_o)
{
  double mu = (double)lnS[b] / 65536.0;
  double var = (double)lnQ[b] / 65536.0 - mu*mu;
  *mu_o = (float)mu;
  *rs_o = (float)(1.0 / sqrt(var + 1e-5));
}

// y1[b,m,k] = sum_c g_w[m,c]*xn[b,c,k] + g_b[m]; xn on the fly from xm (lnfin folded)
__global__ __launch_bounds__(256) void k_y1(
    const float* __restrict__ xm, const float* __restrict__ lnS,
    const float* __restrict__ lnQ, const float* __restrict__ gw,
    const float* __restrict__ gb, float* __restrict__ y1)
{
  const int kt = blockIdx.x, b = blockIdx.y;
  __shared__ __align__(16) float GT[128*132];   // [c][o], pad 132
  __shared__ __align__(16) float XN[128*68];    // [c][k], pad 68
  const int t = threadIdx.x;
  const int k0 = kt*64;
  float mu, rs;
  ln_coeff(lnS, lnQ, b, &mu, &rs);
  #pragma unroll
  for(int i=0;i<16;++i){
    int idx = t + i*256;                 // 4096 f4 units
    int c4 = (idx & 31)*4, o = idx >> 5;
    float4 v = *(const float4*)&gw[o*128 + c4];
    GT[(c4+0)*132 + o] = v.x; GT[(c4+1)*132 + o] = v.y;
    GT[(c4+2)*132 + o] = v.z; GT[(c4+3)*132 + o] = v.w;
  }
  #pragma unroll
  for(int i=0;i<8;++i){
    int idx = t + i*256;                 // 2048 f4 units
    int kk4 = (idx & 15)*4, c = idx >> 4;
    float4 v = *(const float4*)&xm[((size_t)b*128 + c)*512 + k0 + kk4];
    XN[c*68 + kk4 + 0] = (v.x - mu)*rs; XN[c*68 + kk4 + 1] = (v.y - mu)*rs;
    XN[c*68 + kk4 + 2] = (v.z - mu)*rs; XN[c*68 + kk4 + 3] = (v.w - mu)*rs;
  }
  __syncthreads();
  const int tx = t & 15, ty = t >> 4;
  float acc[8][4] = {{0}};
  for(int c=0;c<128;++c){
    f32x4 a0 = *(const f32x4*)&GT[c*132 + ty*8];
    f32x4 a1 = *(const f32x4*)&GT[c*132 + ty*8 + 4];
    f32x4 bv = *(const f32x4*)&XN[c*68 + tx*4];
    #pragma unroll
    for(int j=0;j<4;++j){
      #pragma unroll
      for(int i=0;i<4;++i){ acc[i][j] += a0[i]*bv[j]; acc[i+4][j] += a1[i]*bv[j]; }
    }
  }
  #pragma unroll
  for(int i=0;i<8;++i){
    int m = ty*8 + i;
    float bias = gb[m];
    f32x4 o;
    #pragma unroll
    for(int j=0;j<4;++j) o[j] = acc[i][j] + bias;
    *(f32x4*)&y1[((size_t)b*128 + m)*512 + k0 + tx*4] = o;
  }
}

// Fused attention (f, sm, y2, y3, ystats). Block = (ht, b): 32 h-rows.
// S[32][512] in LDS, two-pass softmax, P*y1^T, out_w*y2 + BN2 stat slot-atomics.
__global__ __launch_bounds__(256) void k_att(
    const float* __restrict__ xm, const float* __restrict__ lnS,
    const float* __restrict__ lnQ, const float* __restrict__ y1,
    const float* __restrict__ ow, const float* __restrict__ obv,
    float* __restrict__ y3,
    float* __restrict__ SyS, float* __restrict__ SyyS, float* __restrict__ SxyS)
{
  const int ht = blockIdx.x, b = blockIdx.y;
  const int h0 = ht*32;
  const int SP = 528;                       // S row stride
  __shared__ __align__(16) float S[32*528]; // 67.6 KB; also reused as OWT[128][132]
  __shared__ __align__(16) float XH[128*32];// 16.4 KB
  __shared__ __align__(16) float BUF[8704]; // 34.8 KB
  const int t = threadIdx.x;
  const int tx = t & 15, ty = t >> 4;
  const int lane = t & 63, wv = t >> 6;
  float mu, rs;
  ln_coeff(lnS, lnQ, b, &mu, &rs);
  const float* xb = xm + (size_t)b*128*512;
  #pragma unroll
  for(int i=0;i<4;++i){
    int idx = t + i*256;
    int hh4 = (idx & 7)*4, c = idx >> 3;
    float4 v = *(const float4*)&xb[(size_t)c*512 + h0 + hh4];
    XH[c*32 + hh4 + 0] = (v.x - mu)*rs; XH[c*32 + hh4 + 1] = (v.y - mu)*rs;
    XH[c*32 + hh4 + 2] = (v.z - mu)*rs; XH[c*32 + hh4 + 3] = (v.w - mu)*rs;
  }
  const float sscale = 0.088388347648318447f;
  for(int kt=0;kt<8;++kt){
    int k0 = kt*64;
    #pragma unroll
    for(int i=0;i<8;++i){
      int idx = t + i*256;
      int kk4 = (idx & 15)*4, c = idx >> 4;
      float4 v = *(const float4*)&xb[(size_t)c*512 + k0 + kk4];
      BUF[c*68 + kk4 + 0] = (v.x - mu)*rs; BUF[c*68 + kk4 + 1] = (v.y - mu)*rs;
      BUF[c*68 + kk4 + 2] = (v.z - mu)*rs; BUF[c*68 + kk4 + 3] = (v.w - mu)*rs;
    }
    __syncthreads();
    float acc[2][4] = {{0}};
    for(int c=0;c<128;++c){
      float a0 = XH[c*32 + ty*2];
      float a1 = XH[c*32 + ty*2 + 1];
      f32x4 bv = *(const f32x4*)&BUF[c*68 + tx*4];
      #pragma unroll
      for(int j=0;j<4;++j){ acc[0][j] += a0*bv[j]; acc[1][j] += a1*bv[j]; }
    }
    #pragma unroll
    for(int i=0;i<2;++i){
      f32x4 o;
      #pragma unroll
      for(int j=0;j<4;++j) o[j] = acc[i][j]*sscale;
      *(f32x4*)&S[(ty*2+i)*SP + k0 + tx*4] = o;
    }
    __syncthreads();
  }
  #pragma unroll
  for(int rr=0;rr<8;++rr){
    int row = wv*8 + rr;
    float* rowp = &S[row*SP];
    f32x4 v0 = *(const f32x4*)&rowp[lane*8];
    f32x4 v1 = *(const f32x4*)&rowp[lane*8 + 4];
    float mx = v0[0];
    #pragma unroll
    for(int j=1;j<4;++j) mx = fmaxf(mx, v0[j]);
    #pragma unroll
    for(int j=0;j<4;++j) mx = fmaxf(mx, v1[j]);
    #pragma unroll
    for(int m=1;m<64;m<<=1) mx = fmaxf(mx, __shfl_xor(mx, m));
    float sum = 0.f;
    #pragma unroll
    for(int j=0;j<4;++j){ v0[j] = __expf(v0[j]-mx); sum += v0[j]; }
    #pragma unroll
    for(int j=0;j<4;++j){ v1[j] = __expf(v1[j]-mx); sum += v1[j]; }
    #pragma unroll
    for(int m=1;m<64;m<<=1) sum += __shfl_xor(sum, m);
    float inv = 1.f / sum;
    #pragma unroll
    for(int j=0;j<4;++j){ v0[j] *= inv; v1[j] *= inv; }
    *(f32x4*)&rowp[lane*8] = v0;
    *(f32x4*)&rowp[lane*8+4] = v1;
  }
  __syncthreads();
  float y2a[2][8] = {{0}};
  for(int kt=0;kt<8;++kt){
    int k0 = kt*64;
    #pragma unroll
    for(int i=0;i<8;++i){
      int idx = t + i*256;
      int kk4 = (idx & 15)*4, m = idx >> 4;
      float4 v = *(const float4*)&y1[((size_t)b*128 + m)*512 + k0 + kk4];
      BUF[(kk4+0)*132 + m] = v.x; BUF[(kk4+1)*132 + m] = v.y;
      BUF[(kk4+2)*132 + m] = v.z; BUF[(kk4+3)*132 + m] = v.w;
    }
    __syncthreads();
    for(int kk=0;kk<64;++kk){
      float a0 = S[(ty*2)*SP + k0 + kk];
      float a1 = S[(ty*2+1)*SP + k0 + kk];
      f32x4 b0 = *(const f32x4*)&BUF[kk*132 + tx*8];
      f32x4 b1 = *(const f32x4*)&BUF[kk*132 + tx*8 + 4];
      #pragma unroll
      for(int j=0;j<4;++j){
        y2a[0][j]   += a0*b0[j]; y2a[1][j]   += a1*b0[j];
        y2a[0][j+4] += a0*b1[j]; y2a[1][j+4] += a1*b1[j];
      }
    }
    __syncthreads();
  }
  #pragma unroll
  for(int i=0;i<2;++i)
    #pragma unroll
    for(int j=0;j<8;++j)
      BUF[(ty*2+i)*131 + tx*8 + j] = y2a[i][j];
  float* OWT = S;
  #pragma unroll
  for(int i=0;i<16;++i){
    int idx = t + i*256;
    int m4 = (idx & 31)*4, o = idx >> 5;
    float4 v = *(const float4*)&ow[o*128 + m4];
    OWT[(m4+0)*132 + o] = v.x; OWT[(m4+1)*132 + o] = v.y;
    OWT[(m4+2)*132 + o] = v.z; OWT[(m4+3)*132 + o] = v.w;
  }
  __syncthreads();
  float a2[2][8] = {{0}};
  for(int m=0;m<128;++m){
    f32x4 w0 = *(const f32x4*)&OWT[m*132 + ty*8];
    f32x4 w1 = *(const f32x4*)&OWT[m*132 + ty*8 + 4];
    float h0v = BUF[(tx*2)*131 + m];
    float h1v = BUF[(tx*2+1)*131 + m];
    #pragma unroll
    for(int j=0;j<4;++j){
      a2[0][j]   += w0[j]*h0v; a2[1][j]   += w0[j]*h1v;
      a2[0][j+4] += w1[j]*h0v; a2[1][j+4] += w1[j]*h1v;
    }
  }
  const int slot = ((ht<<4) | b) & 31;
  #pragma unroll
  for(int j=0;j<8;++j){
    int o = ty*8 + j;
    float bias = obv[o];
    float v0 = a2[0][j] + bias;
    float v1 = a2[1][j] + bias;
    size_t off = ((size_t)b*128 + o)*512 + h0 + tx*2;
    float2 st; st.x = v0; st.y = v1;
    *(float2*)&y3[off] = st;
    float2 xv = *(const float2*)&xm[off];
    float sy_ = v0 + v1;
    float syy_ = v0*v0 + v1*v1;
    float sxy_ = v0*xv.x + v1*xv.y;
    #pragma unroll
    for(int m=1;m<16;m<<=1){
      sy_ += __shfl_xor(sy_, m); syy_ += __shfl_xor(syy_, m); sxy_ += __shfl_xor(sxy_, m);
    }
    if(tx == 0){
      atomicAdd(&SyS[o*32 + slot], sy_);
      atomicAdd(&SyyS[o*32 + slot], syy_);
      atomicAdd(&SxyS[o*32 + slot], sxy_);
    }
  }
}

// out = silu(bn2(relu(bn1(conv)) + y3)); bn1fin+bn2fin folded (per-block reduce)
__global__ __launch_bounds__(256) void k_final(
    const unsigned short* __restrict__ craw,
    const float* __restrict__ sum_slots, const float* __restrict__ sq_slots,
    const float* __restrict__ g1, const float* __restrict__ b1,
    const float* __restrict__ Sh, const float* __restrict__ Qh,
    const float* __restrict__ SyS, const float* __restrict__ SyyS,
    const float* __restrict__ SxyS, const float* __restrict__ g2,
    const float* __restrict__ b2, const float* __restrict__ y3,
    float* __restrict__ out)
{
  const int c = blockIdx.x, b = blockIdx.y;
  const int t = threadIdx.x, wv = t >> 6, l = t & 63;
  float a1, c1;
  bn1_coeff(sum_slots, sq_slots, g1, b1, c, &a1, &c1);
  double Sy = 0.0, Syy = 0.0, Sxy = 0.0;
  #pragma unroll
  for(int s=0;s<32;++s){
    Sy  += (double)SyS[c*32+s];
    Syy += (double)SyyS[c*32+s];
    Sxy += (double)SxyS[c*32+s];
  }
  const double N = 524288.0;
  double S2 = (double)Sh[c] + 64.0*Sy;
  double Q2 = (double)Qh[c] + 128.0*Sxy + 64.0*Syy;
  double mu2 = S2/N, var2 = Q2/N - mu2*mu2;
  const float a2 = (float)((double)g2[c] / sqrt(var2 + 1e-5));
  const float c2 = (float)((double)b2[c] - mu2*(double)a2);
  const size_t rb = ((size_t)b*128 + c)*512;
  const unsigned short* base = craw + rb*64;
  const float* yrow = y3 + rb;
  float* ob = out + rb*64;
  for(int it=0; it<16; ++it){
    int row = it*32 + wv*8 + (l >> 3);
    int w0 = (l & 7)*8;
    u32x4 d = __builtin_nontemporal_load((const u32x4*)(base + (size_t)row*64 + w0));
    float yv = yrow[row];
    float r[8]; dec8(d, r);
    f32x4 o0, o1;
    #pragma unroll
    for(int j=0;j<8;++j){
      float h = a1*r[j] + c1; h = h > 0.f ? h : 0.f;
      float z = a2*(h + yv) + c2;
      float val = z * __builtin_amdgcn_rcpf(1.f + __expf(-z));
      if(j < 4) o0[j] = val; else o1[j-4] = val;
    }
    __builtin_nontemporal_store(o0, (f32x4*)(ob + (size_t)row*64 + w0));
    __builtin_nontemporal_store(o1, (f32x4*)(ob + (size_t)row*64 + w0 + 4));
  }
}

extern "C" void kernel_launch(void* const* d_in, const int* in_sizes, int n_in,
                              void* d_out, int out_size, void* d_ws, size_t ws_size,
                              hipStream_t stream)
{
  const float* x      = (const float*)d_in[0];
  const float* conv_w = (const float*)d_in[1];
  const float* bn1_g  = (const float*)d_in[2];
  const float* bn1_b  = (const float*)d_in[3];
  const float* g_w    = (const float*)d_in[4];
  const float* g_b    = (const float*)d_in[5];
  const float* out_w  = (const float*)d_in[6];
  const float* out_b  = (const float*)d_in[7];
  const float* bn2_g  = (const float*)d_in[8];
  const float* bn2_b  = (const float*)d_in[9];
  float* out = (float*)d_out;
  char* ws = (char*)d_ws;

  // ws layout (~138.7 MB); zero region = [0, 115840)
  float* sum_slots = (float*)(ws);              // 128*64 f
  float* sq_slots  = (float*)(ws + 32768);      // 128*64 f
  float* SyS       = (float*)(ws + 65536);      // 128*32 f
  float* SyyS      = (float*)(ws + 81920);      // 128*32 f
  float* SxyS      = (float*)(ws + 98304);      // 128*32 f
  float* Sh        = (float*)(ws + 114688);     // 128 f
  float* Qh        = (float*)(ws + 115200);     // 128 f
  float* lnS       = (float*)(ws + 115712);     // 16 f
  float* lnQ       = (float*)(ws + 115776);     // 16 f -- zero ends 115840
  unsigned short* wA = (unsigned short*)(ws + 116224);     // 147456 B
  float* y3        = (float*)(ws + 263680);                // 4 MB
  unsigned short* craw = (unsigned short*)(ws + 4457984);  // 134217728 B

  // intermediates that die before k_final live in d_out (268 MB) as scratch
  float* xm  = out;                 // 1M floats
  float* y1  = out + 2*(1u<<20);
  unsigned short* xbf = (unsigned short*)((char*)out + (size_t)64*1024*1024); // 67 MB

  hipMemsetAsync(ws, 0, 115840, stream);
  hipLaunchKernelGGL(k_prep,   dim3(288),      dim3(256), 0, stream, conv_w, wA);
  hipLaunchKernelGGL(k_xbf,    dim3(512,16),   dim3(256), 0, stream, x, xbf);
  hipLaunchKernelGGL(k_conv,   dim3(128,16),   dim3(256), 0, stream, xbf, wA, craw, sum_slots, sq_slots);
  hipLaunchKernelGGL(k_passB,  dim3(128,16),   dim3(256), 0, stream, craw, sum_slots, sq_slots, bn1_g, bn1_b, xm, Sh, Qh, lnS, lnQ);
  hipLaunchKernelGGL(k_y1,     dim3(8,16),     dim3(256), 0, stream, xm, lnS, lnQ, g_w, g_b, y1);
  hipLaunchKernelGGL(k_att,    dim3(16,16),    dim3(256), 0, stream, xm, lnS, lnQ, y1, out_w, out_b, y3, SyS, SyyS, SxyS);
  hipLaunchKernelGGL(k_final,  dim3(128,16),   dim3(256), 0, stream, craw, sum_slots, sq_slots, bn1_g, bn1_b, Sh, Qh, SyS, SyyS, SxyS, bn2_g, bn2_b, y3, out);
}

// Round 6
// 665.742 us; speedup vs baseline: 1.3038x; 1.0428x over previous
//
#include <hip/hip_runtime.h>
#include <stdint.h>

typedef __attribute__((ext_vector_type(8))) short short8;
typedef __attribute__((ext_vector_type(4))) float f32x4;
typedef __attribute__((ext_vector_type(4))) unsigned int u32x4;
typedef __attribute__((ext_vector_type(2))) unsigned int u32x2;

typedef const __attribute__((address_space(1))) unsigned int* gas_u32p;
typedef __attribute__((address_space(3))) unsigned int* las_u32p;

__device__ __forceinline__ unsigned short f2bf(float f){
  union{float f; unsigned u;} v; v.f = f;
  unsigned r = v.u + 0x7FFFu + ((v.u >> 16) & 1u);
  return (unsigned short)(r >> 16);
}
__device__ __forceinline__ void dec8(u32x4 d, float* r){
  union{unsigned a; float f;} t;
  t.a = (d[0] & 0xFFFFu) << 16; r[0]=t.f; t.a = d[0] & 0xFFFF0000u; r[1]=t.f;
  t.a = (d[1] & 0xFFFFu) << 16; r[2]=t.f; t.a = d[1] & 0xFFFF0000u; r[3]=t.f;
  t.a = (d[2] & 0xFFFFu) << 16; r[4]=t.f; t.a = d[2] & 0xFFFF0000u; r[5]=t.f;
  t.a = (d[3] & 0xFFFFu) << 16; r[6]=t.f; t.a = d[3] & 0xFFFF0000u; r[7]=t.f;
}
__device__ __forceinline__ void dec4(u32x2 d, float* r){
  union{unsigned a; float f;} t;
  t.a = (d[0] & 0xFFFFu) << 16; r[0]=t.f; t.a = d[0] & 0xFFFF0000u; r[1]=t.f;
  t.a = (d[1] & 0xFFFFu) << 16; r[2]=t.f; t.a = d[1] & 0xFFFF0000u; r[3]=t.f;
}

// Pack conv_w [128][64][3][3] -> wA [ks=18][m=128][kk=32] bf16, k = (dh*3+dw)*64 + cin
__global__ __launch_bounds__(256) void k_prep(const float* __restrict__ cw,
                                              unsigned short* __restrict__ wA){
  int i = blockIdx.x*256 + threadIdx.x;
  if(i >= 18*128*32) return;
  int kk = i & 31, m = (i >> 5) & 127, ks = i >> 12;
  int k = ks*32 + kk;
  int pos = k >> 6, cin = k & 63;
  int dh = pos/3, dw = pos - dh*3;
  wA[i] = f2bf(cw[((m*64 + cin)*3 + dh)*3 + dw]);
}

// Transpose+convert x [b][c][h][w] fp32 -> xbf [b][h][w][c] bf16.
__global__ __launch_bounds__(256) void k_xbf(const float* __restrict__ x,
                                             unsigned short* __restrict__ xbf){
  const int h = blockIdx.x, b = blockIdx.y;
  __shared__ float L[64][65];
  const int t = threadIdx.x;
  #pragma unroll
  for(int i=0;i<4;++i){
    int idx = i*256 + t;            // 1024 float4 units
    int c = idx >> 4, w0 = (idx & 15) * 4;
    const float* p = x + (((size_t)b*64 + c)*512 + h)*64 + w0;
    f32x4 v = __builtin_nontemporal_load((const f32x4*)p);
    L[c][w0] = v[0]; L[c][w0+1] = v[1]; L[c][w0+2] = v[2]; L[c][w0+3] = v[3];
  }
  __syncthreads();
  unsigned short* dst = xbf + (((size_t)b*512 + h) << 12);
  #pragma unroll
  for(int i=0;i<8;++i){
    int idx = i*256 + t;            // 2048 u32 units
    int w = idx >> 5, c2 = (idx & 31)*2;
    unsigned pk = (unsigned)f2bf(L[c2][w]) | ((unsigned)f2bf(L[c2+1][w]) << 16);
    *(unsigned*)(dst + (w<<6) + c2) = pk;
  }
}

// Implicit-GEMM conv: block = (b, 4 output rows). Each wave owns one 64-w row:
// acc[8][4] (M=128 x N=64 per wave, K=576, 576 MFMA/wave).
// Fragment n-map: n = 4*r15 + nt -> each lane owns 4 consecutive w.
// LDS swizzle: granule XOR (w>>2)&7, folded into pre-swizzled global source.
// Weights double-buffered in LDS via global_load_lds (2-phase pipeline).
__global__ __launch_bounds__(256, 2) void k_conv(
    const unsigned short* __restrict__ xbf, const unsigned short* __restrict__ wA,
    unsigned short* __restrict__ craw, float* __restrict__ sum_slots,
    float* __restrict__ sq_slots)
{
  const int b = blockIdx.y;
  const int bx = blockIdx.x;                 // 0..127
  const int hx = (bx & 7)*16 + (bx >> 3);    // XCD swizzle, bijective (128 = 8*16)
  const int h0 = hx * 4;
  __shared__ __align__(16) unsigned short xs[6*4096];     // 48 KB linear
  __shared__ __align__(16) unsigned short wbuf[2][4096];  // 16 KB dbuf
  __shared__ float red[2][128];
  const int t = threadIdx.x;
  const int lane = t & 63, wv = t >> 6;
  // stage 6 halo rows (rows h0-1 .. h0+4), 8 KB each via global_load_lds dwordx4
  for(int r = wv; r < 6; r += 4){
    int hin = h0 - 1 + r;
    hin = hin < 0 ? 1 : (hin > 511 ? 510 : hin);   // reflect pad
    const unsigned short* rsrc = xbf + (((size_t)b*512 + hin) << 12);
    unsigned short* ldsrow = &xs[r*4096];
    #pragma unroll
    for(int it=0; it<8; ++it){
      int o = it*1024 + lane*16;                   // byte offset within 8 KB row
      int w = o >> 7;
      int q = o & 127;
      int so = (w << 7) + (q ^ (((w >> 2) & 7) << 4));   // pre-swizzled source
      __builtin_amdgcn_global_load_lds(
          (gas_u32p)(const void*)((const char*)rsrc + so),
          (las_u32p)(void*)(ldsrow + it*512), 16, 0, 0);
    }
  }
  // stage wbuf[0] (ks=0 weight tile, 8 KB linear)
  #pragma unroll
  for(int j=0;j<2;++j){
    int off = j*2048 + wv*512;                     // shorts, wave-uniform
    __builtin_amdgcn_global_load_lds(
        (gas_u32p)(const void*)(wA + off + lane*8),
        (las_u32p)(void*)(&wbuf[0][off]), 16, 0, 0);
  }
  const int r15 = lane & 15, quad = lane >> 4;
  // Precompute swizzled LDS byte-offsets: nt covers w = 4*r15 + nt
  int P[4][3];
  #pragma unroll
  for(int nt=0;nt<4;++nt){
    int wn = 4*r15 + nt;
    #pragma unroll
    for(int dw=0;dw<3;++dw){
      int wi = wn + dw - 1;
      wi = wi < 0 ? 1 : (wi > 63 ? 62 : wi);     // reflect pad
      int s = ((wi >> 2) & 7) << 4;
      P[nt][dw] = (wi << 7) + ((quad*16) ^ (s & 0x30)) + (s & 0x40);
    }
  }
  f32x4 acc[8][4];
  #pragma unroll
  for(int mt=0;mt<8;++mt)
    #pragma unroll
    for(int nt=0;nt<4;++nt){ f32x4 z = {0.f,0.f,0.f,0.f}; acc[mt][nt] = z; }
  __syncthreads();                                // xs + wbuf[0] ready
  const char* xsb = (const char*)xs;
  #pragma unroll
  for(int ks=0; ks<18; ++ks){
    if(ks < 17){                                  // stage next weight tile early
      const unsigned short* wsrc = wA + (ks+1)*4096;
      unsigned short* wdst = &wbuf[(ks+1)&1][0];
      #pragma unroll
      for(int j=0;j<2;++j){
        int off = j*2048 + wv*512;
        __builtin_amdgcn_global_load_lds(
            (gas_u32p)(const void*)(wsrc + off + lane*8),
            (las_u32p)(void*)(wdst + off), 16, 0, 0);
      }
    }
    const int pos = ks >> 1;
    const int dh = pos/3, dw = pos - dh*3;
    const int kbit = (ks & 1) << 6;
    const int rowoff = (wv + dh)*8192;
    const unsigned short* wk = &wbuf[ks&1][0];
    short8 a[8];
    #pragma unroll
    for(int mt=0;mt<8;++mt)
      a[mt] = *(const short8*)(wk + mt*512 + r15*32 + quad*8);
    short8 bfr[4];
    #pragma unroll
    for(int nt=0;nt<4;++nt)
      bfr[nt] = *(const short8*)(xsb + rowoff + (P[nt][dw] ^ kbit));
    __builtin_amdgcn_s_setprio(1);
    #pragma unroll
    for(int mt=0;mt<8;++mt){
      #pragma unroll
      for(int nt=0;nt<4;++nt)
        acc[mt][nt] = __builtin_amdgcn_mfma_f32_16x16x32_bf16(a[mt], bfr[nt], acc[mt][nt], 0,0,0);
    }
    __builtin_amdgcn_s_setprio(0);
    __syncthreads();                              // wbuf[next] complete, wbuf[cur] free
  }
  // epilogue: lane owns w = 4*r15..4*r15+3 for co = mt*16+quad*4+rg.
  // One 8B store per (mt,rg); 16 lanes/quad = 128B full line per instruction.
  {
    size_t obase = (((size_t)b*128)*512 + (size_t)(h0+wv))*64 + 4*r15;
    #pragma unroll
    for(int mt=0;mt<8;++mt){
      #pragma unroll
      for(int rg=0;rg<4;++rg){
        int co = mt*16 + quad*4 + rg;
        u32x2 pk;
        pk[0] = (unsigned)f2bf(acc[mt][0][rg]) | ((unsigned)f2bf(acc[mt][1][rg]) << 16);
        pk[1] = (unsigned)f2bf(acc[mt][2][rg]) | ((unsigned)f2bf(acc[mt][3][rg]) << 16);
        *(u32x2*)(craw + obase + (size_t)co*32768) = pk;
      }
    }
  }
  // BN1 stats: per-cout sum/sumsq
  if(t < 128){ red[0][t] = 0.f; red[1][t] = 0.f; }
  __syncthreads();
  #pragma unroll
  for(int mt=0;mt<8;++mt){
    #pragma unroll
    for(int rg=0;rg<4;++rg){
      float s = acc[mt][0][rg] + acc[mt][1][rg] + acc[mt][2][rg] + acc[mt][3][rg];
      float q = acc[mt][0][rg]*acc[mt][0][rg] + acc[mt][1][rg]*acc[mt][1][rg]
              + acc[mt][2][rg]*acc[mt][2][rg] + acc[mt][3][rg]*acc[mt][3][rg];
      #pragma unroll
      for(int m=1;m<16;m<<=1){ s += __shfl_xor(s, m); q += __shfl_xor(q, m); }
      if(r15 == 0){
        int co = mt*16 + quad*4 + rg;
        atomicAdd(&red[0][co], s);
        atomicAdd(&red[1][co], q);
      }
    }
  }
  __syncthreads();
  if(t < 128){
    int slot = bx & 63;
    atomicAdd(&sum_slots[t*64 + slot], red[0][t]);
    atomicAdd(&sq_slots[t*64 + slot], red[1][t]);
  }
}

__device__ __forceinline__ void bn1_coeff(
    const float* sum_slots, const float* sq_slots,
    const float* g1, const float* b1, int c, float* a1, float* c1)
{
  double S = 0.0, Q = 0.0;
  #pragma unroll
  for(int s=0;s<64;++s){ S += (double)sum_slots[c*64+s]; Q += (double)sq_slots[c*64+s]; }
  const double N = 524288.0;
  double mu = S/N, var = Q/N - mu*mu;
  float sc = (float)((double)g1[c] / sqrt(var + 1e-5));
  *a1 = sc;
  *c1 = (float)((double)b1[c] - mu*(double)sc);
}

// read conv_raw, h=relu(bn1), emit xm=mean_w(h), S_h/Q_h per channel, LN partials per batch
__global__ __launch_bounds__(256) void k_passB(
    const unsigned short* __restrict__ craw,
    const float* __restrict__ sum_slots, const float* __restrict__ sq_slots,
    const float* __restrict__ g1, const float* __restrict__ b1,
    float* __restrict__ xm,
    float* __restrict__ Sh, float* __restrict__ Qh,
    float* __restrict__ lnS, float* __restrict__ lnQ)
{
  const int c = blockIdx.x, b = blockIdx.y;
  const int t = threadIdx.x, wv = t >> 6, l = t & 63;
  float sc, sf;
  bn1_coeff(sum_slots, sq_slots, g1, b1, c, &sc, &sf);
  const unsigned short* base = craw + (((size_t)b*128 + c)*512)*64;
  float* xrow = xm + ((size_t)b*128 + c)*512;
  float sa = 0.f, qa = 0.f, la = 0.f;
  for(int it=0; it<16; ++it){
    int row = it*32 + wv*8 + (l >> 3);
    int w0 = (l & 7)*8;
    u32x4 d = *(const u32x4*)(base + (size_t)row*64 + w0);
    float r[8]; dec8(d, r);
    float tot = 0.f;
    #pragma unroll
    for(int j=0;j<8;++j){
      float v = sc*r[j] + sf;
      v = v > 0.f ? v : 0.f;
      tot += v; sa += v; qa += v*v;
    }
    tot += __shfl_xor(tot, 1); tot += __shfl_xor(tot, 2); tot += __shfl_xor(tot, 4);
    if((l & 7) == 0){
      float mv = tot * (1.f/64.f);
      xrow[row] = mv;
      la += mv*mv;
    }
  }
  #pragma unroll
  for(int m=1;m<64;m<<=1){
    sa += __shfl_xor(sa, m); qa += __shfl_xor(qa, m); la += __shfl_xor(la, m);
  }
  __shared__ float rs[4], rq[4], rl[4];
  if(l == 0){ rs[wv]=sa; rq[wv]=qa; rl[wv]=la; }
  __syncthreads();
  if(t == 0){
    float S = rs[0]+rs[1]+rs[2]+rs[3];
    float Q = rq[0]+rq[1]+rq[2]+rq[3];
    float L = rl[0]+rl[1]+rl[2]+rl[3];
    atomicAdd(&Sh[c], S);
    atomicAdd(&Qh[c], Q);
    atomicAdd(&lnS[b], S * (1.f/64.f));
    atomicAdd(&lnQ[b], L);
  }
}

__device__ __forceinline__ void ln_coeff(const float* lnS, const float* lnQ,
                                         int b, float* mu_o, float* rs_o)
{
  double mu = (double)lnS[b] / 65536.0;
  double var = (double)lnQ[b] / 65536.0 - mu*mu;
  *mu_o = (float)mu;
  *rs_o = (float)(1.0 / sqrt(var + 1e-5));
}

// y1[b,m,k] = sum_c g_w[m,c]*xn[b,c,k] + g_b[m]; xn on the fly from xm (lnfin folded)
__global__ __launch_bounds__(256) void k_y1(
    const float* __restrict__ xm, const float* __restrict__ lnS,
    const float* __restrict__ lnQ, const float* __restrict__ gw,
    const float* __restrict__ gb, float* __restrict__ y1)
{
  const int kt = blockIdx.x, b = blockIdx.y;
  __shared__ __align__(16) float GT[128*132];   // [c][o], pad 132
  __shared__ __align__(16) float XN[128*68];    // [c][k], pad 68
  const int t = threadIdx.x;
  const int k0 = kt*64;
  float mu, rs;
  ln_coeff(lnS, lnQ, b, &mu, &rs);
  #pragma unroll
  for(int i=0;i<16;++i){
    int idx = t + i*256;                 // 4096 f4 units
    int c4 = (idx & 31)*4, o = idx >> 5;
    float4 v = *(const float4*)&gw[o*128 + c4];
    GT[(c4+0)*132 + o] = v.x; GT[(c4+1)*132 + o] = v.y;
    GT[(c4+2)*132 + o] = v.z; GT[(c4+3)*132 + o] = v.w;
  }
  #pragma unroll
  for(int i=0;i<8;++i){
    int idx = t + i*256;                 // 2048 f4 units
    int kk4 = (idx & 15)*4, c = idx >> 4;
    float4 v = *(const float4*)&xm[((size_t)b*128 + c)*512 + k0 + kk4];
    XN[c*68 + kk4 + 0] = (v.x - mu)*rs; XN[c*68 + kk4 + 1] = (v.y - mu)*rs;
    XN[c*68 + kk4 + 2] = (v.z - mu)*rs; XN[c*68 + kk4 + 3] = (v.w - mu)*rs;
  }
  __syncthreads();
  const int tx = t & 15, ty = t >> 4;
  float acc[8][4] = {{0}};
  for(int c=0;c<128;++c){
    f32x4 a0 = *(const f32x4*)&GT[c*132 + ty*8];
    f32x4 a1 = *(const f32x4*)&GT[c*132 + ty*8 + 4];
    f32x4 bv = *(const f32x4*)&XN[c*68 + tx*4];
    #pragma unroll
    for(int j=0;j<4;++j){
      #pragma unroll
      for(int i=0;i<4;++i){ acc[i][j] += a0[i]*bv[j]; acc[i+4][j] += a1[i]*bv[j]; }
    }
  }
  #pragma unroll
  for(int i=0;i<8;++i){
    int m = ty*8 + i;
    float bias = gb[m];
    f32x4 o;
    #pragma unroll
    for(int j=0;j<4;++j) o[j] = acc[i][j] + bias;
    *(f32x4*)&y1[((size_t)b*128 + m)*512 + k0 + tx*4] = o;
  }
}

// Fused attention. Block = (ht, b): 16 h-rows (QBLK=16 -> 75 KB LDS -> 2 blocks/CU).
// S[16][528] in LDS, two-pass softmax, P*y1^T, out_w*y2 (4x32-row chunks) + BN2 stats.
__global__ __launch_bounds__(256) void k_att(
    const float* __restrict__ xm, const float* __restrict__ lnS,
    const float* __restrict__ lnQ, const float* __restrict__ y1,
    const float* __restrict__ ow, const float* __restrict__ obv,
    float* __restrict__ y3,
    float* __restrict__ SyS, float* __restrict__ SyyS, float* __restrict__ SxyS)
{
  const int ht = blockIdx.x, b = blockIdx.y;   // ht 0..31
  const int h0 = ht*16;
  const int SP = 528;
  __shared__ __align__(16) float S[16*528];   // 33.8 KB; reused as OWT[32][132] chunks
  __shared__ __align__(16) float XH[128*16];  // 8.2 KB
  __shared__ __align__(16) float BUF[8704];   // 34.8 KB: XK / Y1T / Y2L[16][131]
  const int t = threadIdx.x;
  const int tx = t & 15, ty = t >> 4;
  const int lane = t & 63, wv = t >> 6;
  float mu, rs;
  ln_coeff(lnS, lnQ, b, &mu, &rs);
  const float* xb = xm + (size_t)b*128*512;
  // stage XH[c][hh] = xn[b,c,h0+hh], 2048 floats
  #pragma unroll
  for(int i=0;i<2;++i){
    int idx = t + i*256;                 // 512 f4
    int hh4 = (idx & 3)*4, c = idx >> 2;
    float4 v = *(const float4*)&xb[(size_t)c*512 + h0 + hh4];
    XH[c*16 + hh4 + 0] = (v.x - mu)*rs; XH[c*16 + hh4 + 1] = (v.y - mu)*rs;
    XH[c*16 + hh4 + 2] = (v.z - mu)*rs; XH[c*16 + hh4 + 3] = (v.w - mu)*rs;
  }
  const float sscale = 0.088388347648318447f;
  // pass 1: S[h][k]
  for(int kt=0;kt<8;++kt){
    int k0 = kt*64;
    #pragma unroll
    for(int i=0;i<8;++i){
      int idx = t + i*256;               // 2048 f4
      int kk4 = (idx & 15)*4, c = idx >> 4;
      float4 v = *(const float4*)&xb[(size_t)c*512 + k0 + kk4];
      BUF[c*68 + kk4 + 0] = (v.x - mu)*rs; BUF[c*68 + kk4 + 1] = (v.y - mu)*rs;
      BUF[c*68 + kk4 + 2] = (v.z - mu)*rs; BUF[c*68 + kk4 + 3] = (v.w - mu)*rs;
    }
    __syncthreads();
    float acc[4] = {0,0,0,0};
    for(int c=0;c<128;++c){
      float a0 = XH[c*16 + ty];
      f32x4 bv = *(const f32x4*)&BUF[c*68 + tx*4];
      #pragma unroll
      for(int j=0;j<4;++j) acc[j] += a0*bv[j];
    }
    f32x4 o;
    #pragma unroll
    for(int j=0;j<4;++j) o[j] = acc[j]*sscale;
    *(f32x4*)&S[ty*SP + k0 + tx*4] = o;
    __syncthreads();
  }
  // pass 2: softmax (wave wv owns rows wv*4..wv*4+3)
  #pragma unroll
  for(int rr=0;rr<4;++rr){
    int row = wv*4 + rr;
    float* rowp = &S[row*SP];
    f32x4 v0 = *(const f32x4*)&rowp[lane*8];
    f32x4 v1 = *(const f32x4*)&rowp[lane*8 + 4];
    float mx = v0[0];
    #pragma unroll
    for(int j=1;j<4;++j) mx = fmaxf(mx, v0[j]);
    #pragma unroll
    for(int j=0;j<4;++j) mx = fmaxf(mx, v1[j]);
    #pragma unroll
    for(int m=1;m<64;m<<=1) mx = fmaxf(mx, __shfl_xor(mx, m));
    float sum = 0.f;
    #pragma unroll
    for(int j=0;j<4;++j){ v0[j] = __expf(v0[j]-mx); sum += v0[j]; }
    #pragma unroll
    for(int j=0;j<4;++j){ v1[j] = __expf(v1[j]-mx); sum += v1[j]; }
    #pragma unroll
    for(int m=1;m<64;m<<=1) sum += __shfl_xor(sum, m);
    float inv = 1.f / sum;
    #pragma unroll
    for(int j=0;j<4;++j){ v0[j] *= inv; v1[j] *= inv; }
    *(f32x4*)&rowp[lane*8] = v0;
    *(f32x4*)&rowp[lane*8+4] = v1;
  }
  __syncthreads();
  // pass 3: y2[h][m] = sum_k P[h][k] * y1[b,m,k]; thread owns h=ty, m=tx*8..+8
  float y2a[8] = {0,0,0,0,0,0,0,0};
  for(int kt=0;kt<8;++kt){
    int k0 = kt*64;
    #pragma unroll
    for(int i=0;i<8;++i){
      int idx = t + i*256;               // 2048 f4
      int kk4 = (idx & 15)*4, m = idx >> 4;
      float4 v = *(const float4*)&y1[((size_t)b*128 + m)*512 + k0 + kk4];
      BUF[(kk4+0)*132 + m] = v.x; BUF[(kk4+1)*132 + m] = v.y;
      BUF[(kk4+2)*132 + m] = v.z; BUF[(kk4+3)*132 + m] = v.w;
    }
    __syncthreads();
    for(int kk=0;kk<64;++kk){
      float a0 = S[ty*SP + k0 + kk];
      f32x4 b0 = *(const f32x4*)&BUF[kk*132 + tx*8];
      f32x4 b1 = *(const f32x4*)&BUF[kk*132 + tx*8 + 4];
      #pragma unroll
      for(int j=0;j<4;++j){ y2a[j] += a0*b0[j]; y2a[j+4] += a0*b1[j]; }
    }
    __syncthreads();
  }
  // spill y2 to Y2L[h][m] (pad 131) in BUF
  #pragma unroll
  for(int j=0;j<8;++j)
    BUF[ty*131 + tx*8 + j] = y2a[j];
  // pass 4: y3[o][h] = sum_m ow[o][m]*y2[h][m], m in 4 chunks of 32 staged into S region
  float* OWT = S;                        // 32*132 = 4224 floats per chunk
  float a2[8] = {0,0,0,0,0,0,0,0};
  for(int mc=0;mc<4;++mc){
    #pragma unroll
    for(int i=0;i<4;++i){
      int idx = t + i*256;               // 1024 f4
      int o = idx >> 3, m4 = (idx & 7)*4;
      float4 v = *(const float4*)&ow[o*128 + mc*32 + m4];
      OWT[(m4+0)*132 + o] = v.x; OWT[(m4+1)*132 + o] = v.y;
      OWT[(m4+2)*132 + o] = v.z; OWT[(m4+3)*132 + o] = v.w;
    }
    __syncthreads();
    for(int mm=0;mm<32;++mm){
      f32x4 w0 = *(const f32x4*)&OWT[mm*132 + ty*8];
      f32x4 w1 = *(const f32x4*)&OWT[mm*132 + ty*8 + 4];
      float hv = BUF[tx*131 + mc*32 + mm];
      #pragma unroll
      for(int j=0;j<4;++j){ a2[j] += w0[j]*hv; a2[j+4] += w1[j]*hv; }
    }
    __syncthreads();
  }
  const int slot = ((ht<<4) | b) & 31;
  #pragma unroll
  for(int j=0;j<8;++j){
    int o = ty*8 + j;
    float v0 = a2[j] + obv[o];
    size_t off = ((size_t)b*128 + o)*512 + h0 + tx;
    y3[off] = v0;
    float xv = xm[off];
    float sy_ = v0;
    float syy_ = v0*v0;
    float sxy_ = v0*xv;
    #pragma unroll
    for(int m=1;m<16;m<<=1){
      sy_ += __shfl_xor(sy_, m); syy_ += __shfl_xor(syy_, m); sxy_ += __shfl_xor(sxy_, m);
    }
    if(tx == 0){
      atomicAdd(&SyS[o*32 + slot], sy_);
      atomicAdd(&SyyS[o*32 + slot], syy_);
      atomicAdd(&SxyS[o*32 + slot], sxy_);
    }
  }
}

// out = silu(bn2(relu(bn1(conv)) + y3)); flat addressing, full-line nt stores.
__global__ __launch_bounds__(256) void k_final(
    const unsigned short* __restrict__ craw,
    const float* __restrict__ sum_slots, const float* __restrict__ sq_slots,
    const float* __restrict__ g1, const float* __restrict__ b1,
    const float* __restrict__ Sh, const float* __restrict__ Qh,
    const float* __restrict__ SyS, const float* __restrict__ SyyS,
    const float* __restrict__ SxyS, const float* __restrict__ g2,
    const float* __restrict__ b2, const float* __restrict__ y3,
    float* __restrict__ out)
{
  const int c = blockIdx.x, b = blockIdx.y;
  const int t = threadIdx.x;
  float a1, c1;
  bn1_coeff(sum_slots, sq_slots, g1, b1, c, &a1, &c1);
  double Sy = 0.0, Syy = 0.0, Sxy = 0.0;
  #pragma unroll
  for(int s=0;s<32;++s){
    Sy  += (double)SyS[c*32+s];
    Syy += (double)SyyS[c*32+s];
    Sxy += (double)SxyS[c*32+s];
  }
  const double N = 524288.0;
  double S2 = (double)Sh[c] + 64.0*Sy;
  double Q2 = (double)Qh[c] + 128.0*Sxy + 64.0*Syy;
  double mu2 = S2/N, var2 = Q2/N - mu2*mu2;
  const float a2 = (float)((double)g2[c] / sqrt(var2 + 1e-5));
  const float c2 = (float)((double)b2[c] - mu2*(double)a2);
  const size_t rb = ((size_t)b*128 + c)*512;
  const unsigned short* base = craw + rb*64;
  const float* yrow = y3 + rb;
  float* ob = out + rb*64;
  for(int it=0; it<16; ++it){
    int f0 = it*2048 + t*4;
    int f1 = f0 + 1024;
    u32x2 d0 = *(const u32x2*)(base + f0);
    u32x2 d1 = *(const u32x2*)(base + f1);
    float yv0 = yrow[f0 >> 6];
    float yv1 = yrow[f1 >> 6];
    float r0[4], r1[4];
    dec4(d0, r0); dec4(d1, r1);
    f32x4 o0, o1;
    #pragma unroll
    for(int j=0;j<4;++j){
      float h = a1*r0[j] + c1; h = h > 0.f ? h : 0.f;
      float z = a2*(h + yv0) + c2;
      o0[j] = z * __builtin_amdgcn_rcpf(1.f + __expf(-z));
      float h2 = a1*r1[j] + c1; h2 = h2 > 0.f ? h2 : 0.f;
      float z2 = a2*(h2 + yv1) + c2;
      o1[j] = z2 * __builtin_amdgcn_rcpf(1.f + __expf(-z2));
    }
    __builtin_nontemporal_store(o0, (f32x4*)(ob + f0));
    __builtin_nontemporal_store(o1, (f32x4*)(ob + f1));
  }
}

extern "C" void kernel_launch(void* const* d_in, const int* in_sizes, int n_in,
                              void* d_out, int out_size, void* d_ws, size_t ws_size,
                              hipStream_t stream)
{
  const float* x      = (const float*)d_in[0];
  const float* conv_w = (const float*)d_in[1];
  const float* bn1_g  = (const float*)d_in[2];
  const float* bn1_b  = (const float*)d_in[3];
  const float* g_w    = (const float*)d_in[4];
  const float* g_b    = (const float*)d_in[5];
  const float* out_w  = (const float*)d_in[6];
  const float* out_b  = (const float*)d_in[7];
  const float* bn2_g  = (const float*)d_in[8];
  const float* bn2_b  = (const float*)d_in[9];
  float* out = (float*)d_out;
  char* ws = (char*)d_ws;

  // ws layout (~138.7 MB); zero region = [0, 115840)
  float* sum_slots = (float*)(ws);              // 128*64 f
  float* sq_slots  = (float*)(ws + 32768);      // 128*64 f
  float* SyS       = (float*)(ws + 65536);      // 128*32 f
  float* SyyS      = (float*)(ws + 81920);      // 128*32 f
  float* SxyS      = (float*)(ws + 98304);      // 128*32 f
  float* Sh        = (float*)(ws + 114688);     // 128 f
  float* Qh        = (float*)(ws + 115200);     // 128 f
  float* lnS       = (float*)(ws + 115712);     // 16 f
  float* lnQ       = (float*)(ws + 115776);     // 16 f -- zero ends 115840
  unsigned short* wA = (unsigned short*)(ws + 116224);     // 147456 B
  float* y3        = (float*)(ws + 263680);                // 4 MB
  unsigned short* craw = (unsigned short*)(ws + 4457984);  // 134217728 B

  // intermediates that die before k_final live in d_out (268 MB) as scratch
  float* xm  = out;                 // 1M floats
  float* y1  = out + 2*(1u<<20);
  unsigned short* xbf = (unsigned short*)((char*)out + (size_t)64*1024*1024); // 67 MB

  hipMemsetAsync(ws, 0, 115840, stream);
  hipLaunchKernelGGL(k_prep,   dim3(288),      dim3(256), 0, stream, conv_w, wA);
  hipLaunchKernelGGL(k_xbf,    dim3(512,16),   dim3(256), 0, stream, x, xbf);
  hipLaunchKernelGGL(k_conv,   dim3(128,16),   dim3(256), 0, stream, xbf, wA, craw, sum_slots, sq_slots);
  hipLaunchKernelGGL(k_passB,  dim3(128,16),   dim3(256), 0, stream, craw, sum_slots, sq_slots, bn1_g, bn1_b, xm, Sh, Qh, lnS, lnQ);
  hipLaunchKernelGGL(k_y1,     dim3(8,16),     dim3(256), 0, stream, xm, lnS, lnQ, g_w, g_b, y1);
  hipLaunchKernelGGL(k_att,    dim3(32,16),    dim3(256), 0, stream, xm, lnS, lnQ, y1, out_w, out_b, y3, SyS, SyyS, SxyS);
  hipLaunchKernelGGL(k_final,  dim3(128,16),   dim3(256), 0, stream, craw, sum_slots, sq_slots, bn1_g, bn1_b, Sh, Qh, SyS, SyyS, SxyS, bn2_g, bn2_b, y3, out);
}